// Round 5
// baseline (1883.842 us; speedup 1.0000x reference)
//
#include <hip/hip_runtime.h>
#include <math.h>

#define D 64
#define CHUNK 4096
#define MS_T 256
#define EPT 16          // CHUNK / MS_T
#define MAXNB 800       // >= nb = ceil(n/128); n=100000 -> 782

typedef __attribute__((ext_vector_type(8))) short frag_ab;
typedef __attribute__((ext_vector_type(4))) float frag_cd;

__device__ __forceinline__ unsigned short f2bf(float f) {
    unsigned u = __float_as_uint(f);
    u += 0x7FFFu + ((u >> 16) & 1u);
    return (unsigned short)(u >> 16);
}
__device__ __forceinline__ float bf2f(unsigned short s) {
    return __uint_as_float(((unsigned)s) << 16);
}

// ---------------------------------------------------------------------------
// deg histogram (divisors for the two means). ~15us at measured atomic rate.
// ---------------------------------------------------------------------------
__global__ __launch_bounds__(256) void hist_deg(
    const int* __restrict__ ei, int* __restrict__ deg_col,
    int* __restrict__ deg_row, int n_edges)
{
    int e = blockIdx.x * blockDim.x + threadIdx.x;
    if (e >= n_edges) return;
    atomicAdd(&deg_row[ei[e]], 1);
    atomicAdd(&deg_col[ei[n_edges + e]], 1);
}

// ---------------------------------------------------------------------------
// per-bucket counts = sum of deg over 128-node ranges. One wave per (b,side).
// ---------------------------------------------------------------------------
__global__ __launch_bounds__(256) void bucket_count(
    const int* __restrict__ deg_col, const int* __restrict__ deg_row,
    int* __restrict__ bc_col, int* __restrict__ bc_row, int n, int nb)
{
    int wave = (blockIdx.x * blockDim.x + threadIdx.x) >> 6;
    int lane = threadIdx.x & 63;
    if (wave >= 2 * nb) return;
    int which = wave >= nb;
    int b = which ? wave - nb : wave;
    const int* deg = which ? deg_row : deg_col;
    int i0 = (b << 7) + lane;
    int s = 0;
    if (i0 < n) s += deg[i0];
    if (i0 + 64 < n) s += deg[i0 + 64];
    #pragma unroll
    for (int o = 32; o > 0; o >>= 1) s += __shfl_down(s, o);
    if (lane == 0) (which ? bc_row : bc_col)[b] = s;
}

// ---------------------------------------------------------------------------
// scan 782 bucket counts -> bases; init cursors. One block.
// ---------------------------------------------------------------------------
__global__ __launch_bounds__(64) void bucket_scan(
    const int* __restrict__ bc_col, const int* __restrict__ bc_row,
    int* __restrict__ bbase_col, int* __restrict__ bbase_row,
    int* __restrict__ gcur_col, int* __restrict__ gcur_row, int nb)
{
    int lane = threadIdx.x;
    for (int w = 0; w < 2; ++w) {
        const int* bc = w ? bc_row : bc_col;
        int* bb = w ? bbase_row : bbase_col;
        int* gc = w ? gcur_row : gcur_col;
        int carry = 0;
        for (int b0 = 0; b0 < nb; b0 += 64) {
            int v = (b0 + lane < nb) ? bc[b0 + lane] : 0;
            int x = v;
            #pragma unroll
            for (int o = 1; o < 64; o <<= 1) {
                int u = __shfl_up(x, o);
                if (lane >= o) x += u;
            }
            if (b0 + lane < nb) {
                int e = carry + x - v;
                bb[b0 + lane] = e;
                gc[b0 + lane] = e;
            }
            carry += __shfl(x, 63);
        }
    }
}

// ---------------------------------------------------------------------------
// Multisplit: group edges by dst-bucket (ecol) and src-bucket (erow).
// Entry = ((key & 127) << 17) | other_endpoint  (node ids < 2^17).
// LDS histogram + block scan + staged coalesced-run writes: no random 4B
// scatters -> kills the 16x write amplification seen in scatter_sort.
// ---------------------------------------------------------------------------
__global__ __launch_bounds__(MS_T) void multisplit(
    const int* __restrict__ ei, int n_edges, int nb,
    int* __restrict__ gcur_col, int* __restrict__ gcur_row,
    unsigned* __restrict__ ecol, unsigned* __restrict__ erow)
{
    __shared__ unsigned stage[CHUNK];
    __shared__ int cnt[MAXNB];
    __shared__ int off[MAXNB + 1];
    __shared__ int gb[MAXNB];

    int base = blockIdx.x * CHUNK;
    int cc = n_edges - base;
    if (cc > CHUNK) cc = CHUNK;

    int r[EPT], c[EPT];
    #pragma unroll
    for (int k = 0; k < EPT; ++k) {
        int i = threadIdx.x + k * MS_T;
        if (i < cc) {
            r[k] = ei[base + i];
            c[k] = ei[n_edges + base + i];
        }
    }

    for (int ord = 0; ord < 2; ++ord) {
        int* gcur = ord ? gcur_row : gcur_col;
        unsigned* eout = ord ? erow : ecol;

        for (int t = threadIdx.x; t < nb; t += MS_T) cnt[t] = 0;
        __syncthreads();

        int rk[EPT], bk[EPT];
        #pragma unroll
        for (int k = 0; k < EPT; ++k) {
            int i = threadIdx.x + k * MS_T;
            if (i < cc) {
                int key = ord ? r[k] : c[k];
                bk[k] = key >> 7;
                rk[k] = atomicAdd(&cnt[bk[k]], 1);
            }
        }
        __syncthreads();

        if (threadIdx.x < 64) {           // wave 0: scan + reserve
            int lane = threadIdx.x;
            int carry = 0;
            for (int b0 = 0; b0 < nb; b0 += 64) {
                int v = (b0 + lane < nb) ? cnt[b0 + lane] : 0;
                int x = v;
                #pragma unroll
                for (int o = 1; o < 64; o <<= 1) {
                    int u = __shfl_up(x, o);
                    if (lane >= o) x += u;
                }
                if (b0 + lane < nb) {
                    off[b0 + lane] = carry + x - v;
                    gb[b0 + lane] = atomicAdd(&gcur[b0 + lane], v);
                }
                carry += __shfl(x, 63);
            }
            if (lane == 0) off[nb] = carry;   // == cc
        }
        __syncthreads();

        #pragma unroll
        for (int k = 0; k < EPT; ++k) {
            int i = threadIdx.x + k * MS_T;
            if (i < cc) {
                int key = ord ? r[k] : c[k];
                int oth = ord ? c[k] : r[k];
                stage[off[bk[k]] + rk[k]] =
                    ((unsigned)(key & 127) << 17) | (unsigned)oth;
            }
        }
        __syncthreads();

        for (int t = threadIdx.x; t < cc; t += MS_T) {
            int lo = 0, hi = nb;
            while (hi - lo > 1) {              // largest lo: off[lo] <= t
                int mid = (lo + hi) >> 1;
                if (off[mid] <= t) lo = mid; else hi = mid;
            }
            eout[gb[lo] + (t - off[lo])] = stage[t];
        }
        __syncthreads();
    }
}

// ---------------------------------------------------------------------------
// agg_bucket: one block per 128-node bucket; acc in LDS; ILP-4 gathers of
// X[src]; ds_add_f32 (conflict-free, lane-stride-1). agg = sum/max(deg,1).
// ---------------------------------------------------------------------------
__global__ __launch_bounds__(1024) void agg_bucket(
    const float* __restrict__ X, const unsigned* __restrict__ ecol,
    const int* __restrict__ bbase, const int* __restrict__ bcnt,
    const int* __restrict__ deg_col, float* __restrict__ agg, int n)
{
    __shared__ float acc[128][D];
    int b = blockIdx.x;
    for (int t = threadIdx.x; t < 128 * D; t += 1024) (&acc[0][0])[t] = 0.f;
    __syncthreads();

    int e0 = bbase[b], ec = bcnt[b];
    int lane = threadIdx.x & 63;
    int w = threadIdx.x >> 6;          // 16 waves

    for (int wb = w * 64; wb < ec; wb += 1024) {
        int m = ec - wb;
        if (m > 64) m = 64;
        unsigned ent = (lane < m) ? ecol[e0 + wb + lane] : 0u;
        int j = 0;
        for (; j + 4 <= m; j += 4) {
            unsigned a0 = __shfl(ent, j),     a1 = __shfl(ent, j + 1);
            unsigned a2 = __shfl(ent, j + 2), a3 = __shfl(ent, j + 3);
            float v0 = X[((size_t)(a0 & 0x1FFFF) << 6) + lane];
            float v1 = X[((size_t)(a1 & 0x1FFFF) << 6) + lane];
            float v2 = X[((size_t)(a2 & 0x1FFFF) << 6) + lane];
            float v3 = X[((size_t)(a3 & 0x1FFFF) << 6) + lane];
            atomicAdd(&acc[a0 >> 17][lane], v0);
            atomicAdd(&acc[a1 >> 17][lane], v1);
            atomicAdd(&acc[a2 >> 17][lane], v2);
            atomicAdd(&acc[a3 >> 17][lane], v3);
        }
        for (; j < m; ++j) {
            unsigned a = __shfl(ent, j);
            float v = X[((size_t)(a & 0x1FFFF) << 6) + lane];
            atomicAdd(&acc[a >> 17][lane], v);
        }
    }
    __syncthreads();

    int s = threadIdx.x >> 6;
    #pragma unroll
    for (int p = 0; p < 8; ++p, s += 16) {
        int node = (b << 7) + s;
        if (node < n) {
            float d = (float)deg_col[node];
            agg[((size_t)node << 6) + lane] = acc[s][lane] / fmaxf(d, 1.f);
        }
    }
}

// ---------------------------------------------------------------------------
// gate_bucket: mean((hu-hc)^2) = hu^2 - 2*hu*mean(hc) + mean(hc^2).
// acc1 += hc, acc2 += hc^2 per row-slot; finalize with tanh. deg==0 -> 0
// (reference: tanh(0/max(0,1)) = 0; the hu^2 term must vanish too).
// ---------------------------------------------------------------------------
__global__ __launch_bounds__(1024) void gate_bucket(
    const float* __restrict__ h, const unsigned* __restrict__ erow,
    const int* __restrict__ bbase, const int* __restrict__ bcnt,
    const int* __restrict__ deg_row, float* __restrict__ out, int n)
{
    __shared__ float acc1[128][D];
    __shared__ float acc2[128][D];
    int b = blockIdx.x;
    for (int t = threadIdx.x; t < 128 * D; t += 1024) {
        (&acc1[0][0])[t] = 0.f;
        (&acc2[0][0])[t] = 0.f;
    }
    __syncthreads();

    int e0 = bbase[b], ec = bcnt[b];
    int lane = threadIdx.x & 63;
    int w = threadIdx.x >> 6;

    for (int wb = w * 64; wb < ec; wb += 1024) {
        int m = ec - wb;
        if (m > 64) m = 64;
        unsigned ent = (lane < m) ? erow[e0 + wb + lane] : 0u;
        int j = 0;
        for (; j + 4 <= m; j += 4) {
            unsigned a0 = __shfl(ent, j),     a1 = __shfl(ent, j + 1);
            unsigned a2 = __shfl(ent, j + 2), a3 = __shfl(ent, j + 3);
            float v0 = h[((size_t)(a0 & 0x1FFFF) << 6) + lane];
            float v1 = h[((size_t)(a1 & 0x1FFFF) << 6) + lane];
            float v2 = h[((size_t)(a2 & 0x1FFFF) << 6) + lane];
            float v3 = h[((size_t)(a3 & 0x1FFFF) << 6) + lane];
            atomicAdd(&acc1[a0 >> 17][lane], v0);
            atomicAdd(&acc2[a0 >> 17][lane], v0 * v0);
            atomicAdd(&acc1[a1 >> 17][lane], v1);
            atomicAdd(&acc2[a1 >> 17][lane], v1 * v1);
            atomicAdd(&acc1[a2 >> 17][lane], v2);
            atomicAdd(&acc2[a2 >> 17][lane], v2 * v2);
            atomicAdd(&acc1[a3 >> 17][lane], v3);
            atomicAdd(&acc2[a3 >> 17][lane], v3 * v3);
        }
        for (; j < m; ++j) {
            unsigned a = __shfl(ent, j);
            float v = h[((size_t)(a & 0x1FFFF) << 6) + lane];
            atomicAdd(&acc1[a >> 17][lane], v);
            atomicAdd(&acc2[a >> 17][lane], v * v);
        }
    }
    __syncthreads();

    int s = threadIdx.x >> 6;
    #pragma unroll
    for (int p = 0; p < 8; ++p, s += 16) {
        int node = (b << 7) + s;
        if (node < n) {
            float hu = h[((size_t)node << 6) + lane];
            float d = (float)deg_row[node];
            float o = 0.f;
            if (d > 0.f) {
                float m1 = acc1[s][lane] / d;
                float m2 = acc2[s][lane] / d;
                o = tanhf(hu * hu - 2.f * hu * m1 + m2);
            }
            out[((size_t)node << 6) + lane] = o;
        }
    }
}

// ---------------------------------------------------------------------------
// pack_w + linear_mfma: unchanged from R4 (verified, absmax 0.0039).
// ---------------------------------------------------------------------------
__global__ __launch_bounds__(256) void pack_w(
    const float* __restrict__ Wl, const float* __restrict__ Wr,
    unsigned short* __restrict__ wpack)
{
    for (int c = threadIdx.x; c < 8192; c += 256) {
        int j = c & 7;
        int lane = (c >> 3) & 63;
        int tile = (c >> 9) & 7;
        int mat = c >> 12;
        int kc = tile >> 2;
        int nt = tile & 3;
        int krow = (lane >> 4) * 8 + j + kc * 32;
        int col = (lane & 15) + nt * 16;
        const float* W = mat ? Wr : Wl;
        float v = W[krow * 64 + col];
        unsigned short hi = f2bf(v);
        unsigned short lo = f2bf(v - bf2f(hi));
        int base = mat * 8192 + tile * 512 + lane * 8 + j;
        wpack[base] = hi;
        wpack[base + 4096] = lo;
    }
}

__global__ __launch_bounds__(256) void linear_mfma(
    const float* __restrict__ X, const float* __restrict__ agg,
    const unsigned short* __restrict__ wpack, const float* __restrict__ b,
    float* __restrict__ h, int n, int ngroups)
{
    int lane = threadIdx.x & 63;
    int g = (blockIdx.x * blockDim.x + threadIdx.x) >> 6;
    if (g >= ngroups) return;
    int quad = lane >> 4;
    int l15 = lane & 15;

    frag_ab wf[2][2][2][4];
    #pragma unroll
    for (int mat = 0; mat < 2; ++mat)
        #pragma unroll
        for (int hf = 0; hf < 2; ++hf)
            #pragma unroll
            for (int kc = 0; kc < 2; ++kc)
                #pragma unroll
                for (int nt = 0; nt < 4; ++nt) {
                    const unsigned short* p =
                        wpack + mat * 8192 + hf * 4096 + (kc * 4 + nt) * 512 + lane * 8;
                    wf[mat][hf][kc][nt] = *(const frag_ab*)p;
                }

    frag_cd acc[4];
    #pragma unroll
    for (int nt = 0; nt < 4; ++nt) acc[nt] = (frag_cd){0.f, 0.f, 0.f, 0.f};

    int mrow = g * 16 + l15;
    if (mrow >= n) mrow = n - 1;
    const float* arow = agg + ((size_t)mrow << 6) + quad * 8;
    const float* xrow = X + ((size_t)mrow << 6) + quad * 8;

    #pragma unroll
    for (int kc = 0; kc < 2; ++kc) {
        float av[8], xv[8];
        #pragma unroll
        for (int t = 0; t < 2; ++t) {
            float4 a4 = *(const float4*)(arow + kc * 32 + t * 4);
            float4 x4 = *(const float4*)(xrow + kc * 32 + t * 4);
            av[t * 4 + 0] = a4.x; av[t * 4 + 1] = a4.y;
            av[t * 4 + 2] = a4.z; av[t * 4 + 3] = a4.w;
            xv[t * 4 + 0] = x4.x; xv[t * 4 + 1] = x4.y;
            xv[t * 4 + 2] = x4.z; xv[t * 4 + 3] = x4.w;
        }
        frag_ab ah, al, xh, xl;
        #pragma unroll
        for (int j = 0; j < 8; ++j) {
            unsigned short hb = f2bf(av[j]);
            ah[j] = (short)hb;
            al[j] = (short)f2bf(av[j] - bf2f(hb));
            unsigned short xb = f2bf(xv[j]);
            xh[j] = (short)xb;
            xl[j] = (short)f2bf(xv[j] - bf2f(xb));
        }
        #pragma unroll
        for (int nt = 0; nt < 4; ++nt) {
            acc[nt] = __builtin_amdgcn_mfma_f32_16x16x32_bf16(ah, wf[0][0][kc][nt], acc[nt], 0, 0, 0);
            acc[nt] = __builtin_amdgcn_mfma_f32_16x16x32_bf16(ah, wf[0][1][kc][nt], acc[nt], 0, 0, 0);
            acc[nt] = __builtin_amdgcn_mfma_f32_16x16x32_bf16(al, wf[0][0][kc][nt], acc[nt], 0, 0, 0);
            acc[nt] = __builtin_amdgcn_mfma_f32_16x16x32_bf16(xh, wf[1][0][kc][nt], acc[nt], 0, 0, 0);
            acc[nt] = __builtin_amdgcn_mfma_f32_16x16x32_bf16(xh, wf[1][1][kc][nt], acc[nt], 0, 0, 0);
            acc[nt] = __builtin_amdgcn_mfma_f32_16x16x32_bf16(xl, wf[1][0][kc][nt], acc[nt], 0, 0, 0);
        }
    }

    #pragma unroll
    for (int nt = 0; nt < 4; ++nt) {
        float bj = b[l15 + nt * 16];
        #pragma unroll
        for (int r = 0; r < 4; ++r) {
            int row = quad * 4 + r;
            int node = g * 16 + row;
            if (node < n) {
                float v = acc[nt][r] + bj;
                h[((size_t)node << 6) + l15 + nt * 16] = fmaxf(v, 0.f);
            }
        }
    }
}

extern "C" void kernel_launch(void* const* d_in, const int* in_sizes, int n_in,
                              void* d_out, int out_size, void* d_ws, size_t ws_size,
                              hipStream_t stream) {
    const float* X  = (const float*)d_in[0];
    const int*   ei = (const int*)d_in[1];
    const float* Wl = (const float*)d_in[2];
    const float* Wr = (const float*)d_in[3];
    const float* b  = (const float*)d_in[4];
    float* out = (float*)d_out;

    int n = in_sizes[0] / D;
    int n_edges = in_sizes[1] / 2;
    int nb = (n + 127) >> 7;   // 128-node buckets; 782 for n=100000

    // ws layout
    float* agg = (float*)d_ws;                                       // n*64
    float* h   = agg + (size_t)n * D;                                // n*64
    unsigned short* wpack = (unsigned short*)(h + (size_t)n * D);    // 16384
    int* w = (int*)(wpack + 16384);
    int* deg_col   = w;                    // n
    int* deg_row   = deg_col + n;          // n
    int* bc_col    = deg_row + n;          // nb
    int* bc_row    = bc_col + nb;          // nb
    int* bbase_col = bc_row + nb;          // nb
    int* bbase_row = bbase_col + nb;       // nb
    int* gcur_col  = bbase_row + nb;       // nb
    int* gcur_row  = gcur_col + nb;        // nb
    unsigned* ecol = (unsigned*)(gcur_row + nb);   // n_edges
    unsigned* erow = ecol + n_edges;               // n_edges

    hipMemsetAsync(deg_col, 0, (size_t)2 * n * sizeof(int), stream);

    int eb = (n_edges + 255) / 256;
    hist_deg<<<eb, 256, 0, stream>>>(ei, deg_col, deg_row, n_edges);
    bucket_count<<<(2 * nb + 3) / 4, 256, 0, stream>>>(deg_col, deg_row,
                                                       bc_col, bc_row, n, nb);
    bucket_scan<<<1, 64, 0, stream>>>(bc_col, bc_row, bbase_col, bbase_row,
                                      gcur_col, gcur_row, nb);
    multisplit<<<(n_edges + CHUNK - 1) / CHUNK, MS_T, 0, stream>>>(
        ei, n_edges, nb, gcur_col, gcur_row, ecol, erow);

    pack_w<<<1, 256, 0, stream>>>(Wl, Wr, wpack);

    agg_bucket<<<nb, 1024, 0, stream>>>(X, ecol, bbase_col, bc_col, deg_col,
                                        agg, n);

    int ngroups = (n + 15) / 16;
    linear_mfma<<<(ngroups + 3) / 4, 256, 0, stream>>>(X, agg, wpack, b, h, n,
                                                       ngroups);

    gate_bucket<<<nb, 1024, 0, stream>>>(h, erow, bbase_row, bc_row, deg_row,
                                         out, n);
}

// Round 6
// 375.895 us; speedup vs baseline: 5.0116x; 5.0116x over previous
//
#include <hip/hip_runtime.h>
#include <math.h>

#define D 64
#define CHUNK 4096
#define MS_T 256
#define EPT 16          // CHUNK / MS_T
#define MAXNB 800       // >= nbk = ceil(n/128); n=100000 -> 782

typedef __attribute__((ext_vector_type(8))) short frag_ab;
typedef __attribute__((ext_vector_type(4))) float frag_cd;

__device__ __forceinline__ unsigned short f2bf(float f) {
    unsigned u = __float_as_uint(f);
    u += 0x7FFFu + ((u >> 16) & 1u);
    return (unsigned short)(u >> 16);
}
__device__ __forceinline__ float bf2f(unsigned short s) {
    return __uint_as_float(((unsigned)s) << 16);
}

// ---------------------------------------------------------------------------
// degree histogram (global int atomics, ~2.5M ops ~ 15us at 242 G/s measured)
// ---------------------------------------------------------------------------
__global__ __launch_bounds__(256) void hist_deg(
    const int* __restrict__ ei, int* __restrict__ deg_col,
    int* __restrict__ deg_row, int n_edges)
{
    int e = blockIdx.x * blockDim.x + threadIdx.x;
    if (e >= n_edges) return;
    atomicAdd(&deg_row[ei[e]], 1);
    atomicAdd(&deg_col[ei[n_edges + e]], 1);
}

// ---------------------------------------------------------------------------
// node-level exclusive scan (R3-verified 3-kernel chain)
// ---------------------------------------------------------------------------
__global__ __launch_bounds__(1024) void scan_blocks(
    const int* __restrict__ dA, int* __restrict__ oA, int* __restrict__ tA,
    const int* __restrict__ dB, int* __restrict__ oB, int* __restrict__ tB,
    int n, int nbs)
{
    bool isB = blockIdx.x >= (unsigned)nbs;
    const int* d = isB ? dB : dA;
    int* o = isB ? oB : oA;
    int* t = isB ? tB : tA;
    int blk = isB ? (blockIdx.x - nbs) : blockIdx.x;

    int i = blk * 1024 + threadIdx.x;
    int v = (i < n) ? d[i] : 0;

    int lane = threadIdx.x & 63;
    int wid = threadIdx.x >> 6;
    int x = v;
    #pragma unroll
    for (int ofs = 1; ofs < 64; ofs <<= 1) {
        int u = __shfl_up(x, ofs);
        if (lane >= ofs) x += u;
    }
    __shared__ int wtot[16];
    __shared__ int woff[16];
    if (lane == 63) wtot[wid] = x;
    __syncthreads();
    if (threadIdx.x < 64) {
        int wv = (lane < 16) ? wtot[lane] : 0;
        int wx = wv;
        #pragma unroll
        for (int ofs = 1; ofs < 16; ofs <<= 1) {
            int u = __shfl_up(wx, ofs);
            if (lane >= ofs) wx += u;
        }
        if (lane < 16) woff[lane] = wx - wv;
    }
    __syncthreads();
    int excl = (x - v) + woff[wid];
    if (i < n) o[i] = excl;
    if (threadIdx.x == 1023) t[blk] = excl + v;
}

__global__ __launch_bounds__(64) void scan_totals(
    int* __restrict__ tA, int* __restrict__ oA,
    int* __restrict__ tB, int* __restrict__ oB, int nbs, int n)
{
    int* t = blockIdx.x ? tB : tA;
    int* o = blockIdx.x ? oB : oA;
    int lane = threadIdx.x & 63;
    int carry = 0;
    for (int base = 0; base < nbs; base += 64) {
        int v = (base + lane < nbs) ? t[base + lane] : 0;
        int x = v;
        #pragma unroll
        for (int ofs = 1; ofs < 64; ofs <<= 1) {
            int u = __shfl_up(x, ofs);
            if (lane >= ofs) x += u;
        }
        if (base + lane < nbs) t[base + lane] = carry + x - v;
        carry += __shfl(x, 63);
    }
    if (lane == 0) o[n] = carry;
}

__global__ __launch_bounds__(1024) void add_offsets(
    int* __restrict__ oA, const int* __restrict__ tA,
    int* __restrict__ oB, const int* __restrict__ tB, int n, int nbs)
{
    bool isB = blockIdx.x >= (unsigned)nbs;
    int* o = isB ? oB : oA;
    const int* t = isB ? tB : tA;
    int blk = isB ? (blockIdx.x - nbs) : blockIdx.x;
    int i = blk * 1024 + threadIdx.x;
    if (i < n) o[i] += t[blk];
}

// ---------------------------------------------------------------------------
// bucket cursors = CSR offset at each 128-node bucket boundary
// ---------------------------------------------------------------------------
__global__ __launch_bounds__(256) void init_gcur(
    const int* __restrict__ off_col, const int* __restrict__ off_row,
    int* __restrict__ gcur_col, int* __restrict__ gcur_row, int nbk)
{
    int b = blockIdx.x * blockDim.x + threadIdx.x;
    if (b < nbk) {
        gcur_col[b] = off_col[b << 7];
        gcur_row[b] = off_row[b << 7];
    }
}

// ---------------------------------------------------------------------------
// Multisplit: group edges into 128-node buckets for both orderings.
// Entry = ((key & 127) << 17) | other  (node ids < 2^17).
// LDS stage + per-element bucket tag -> fully coalesced run writes.
// Rank atomics are per-thread scalar (cheap), never per-edge-feature.
// ---------------------------------------------------------------------------
__global__ __launch_bounds__(MS_T) void multisplit(
    const int* __restrict__ ei, int n_edges, int nbk,
    int* __restrict__ gcur_col, int* __restrict__ gcur_row,
    unsigned* __restrict__ ecol, unsigned* __restrict__ erow)
{
    __shared__ unsigned stage[CHUNK];
    __shared__ unsigned short sbk[CHUNK];
    __shared__ int cnt[MAXNB];
    __shared__ int off[MAXNB + 1];
    __shared__ int gb[MAXNB];

    int base = blockIdx.x * CHUNK;
    int cc = n_edges - base;
    if (cc > CHUNK) cc = CHUNK;

    int r[EPT], c[EPT];
    #pragma unroll
    for (int k = 0; k < EPT; ++k) {
        int i = threadIdx.x + k * MS_T;
        if (i < cc) {
            r[k] = ei[base + i];
            c[k] = ei[n_edges + base + i];
        }
    }

    for (int ord = 0; ord < 2; ++ord) {
        int* gcur = ord ? gcur_row : gcur_col;
        unsigned* eout = ord ? erow : ecol;

        for (int t = threadIdx.x; t < nbk; t += MS_T) cnt[t] = 0;
        __syncthreads();

        int rk[EPT], bk[EPT];
        #pragma unroll
        for (int k = 0; k < EPT; ++k) {
            int i = threadIdx.x + k * MS_T;
            if (i < cc) {
                int key = ord ? r[k] : c[k];
                bk[k] = key >> 7;
                rk[k] = atomicAdd(&cnt[bk[k]], 1);
            }
        }
        __syncthreads();

        if (threadIdx.x < 64) {           // wave 0: scan + global reservation
            int lane = threadIdx.x;
            int carry = 0;
            for (int b0 = 0; b0 < nbk; b0 += 64) {
                int v = (b0 + lane < nbk) ? cnt[b0 + lane] : 0;
                int x = v;
                #pragma unroll
                for (int o = 1; o < 64; o <<= 1) {
                    int u = __shfl_up(x, o);
                    if (lane >= o) x += u;
                }
                if (b0 + lane < nbk) {
                    off[b0 + lane] = carry + x - v;
                    gb[b0 + lane] = v ? atomicAdd(&gcur[b0 + lane], v) : 0;
                }
                carry += __shfl(x, 63);
            }
        }
        __syncthreads();

        #pragma unroll
        for (int k = 0; k < EPT; ++k) {
            int i = threadIdx.x + k * MS_T;
            if (i < cc) {
                int key = ord ? r[k] : c[k];
                int oth = ord ? c[k] : r[k];
                int p = off[bk[k]] + rk[k];
                stage[p] = ((unsigned)(key & 127) << 17) | (unsigned)oth;
                sbk[p] = (unsigned short)bk[k];
            }
        }
        __syncthreads();

        for (int t = threadIdx.x; t < cc; t += MS_T) {
            int bb = sbk[t];
            eout[gb[bb] + (t - off[bb])] = stage[t];
        }
        __syncthreads();
    }
}

// ---------------------------------------------------------------------------
// Bucket -> exact per-node CSR. Writes land inside the bucket's contiguous
// ~6.4KB window -> lines fill completely, write amp ~1 (vs 16x scatter_sort).
// ---------------------------------------------------------------------------
__global__ __launch_bounds__(256) void bucket_to_csr(
    const unsigned* __restrict__ ecol, const unsigned* __restrict__ erow,
    const int* __restrict__ off_col, const int* __restrict__ off_row,
    int* __restrict__ by_col, int* __restrict__ by_row, int n, int nbk)
{
    __shared__ int soff[129];
    __shared__ int rk[128];
    bool isRow = blockIdx.x >= (unsigned)nbk;
    int b = isRow ? (blockIdx.x - nbk) : blockIdx.x;
    const unsigned* e = isRow ? erow : ecol;
    const int* off = isRow ? off_row : off_col;
    int* by = isRow ? by_row : by_col;

    int node0 = b << 7;
    int nn = n - node0;
    if (nn > 128) nn = 128;
    for (int t = threadIdx.x; t < 128; t += 256) {
        rk[t] = 0;
        soff[t] = (t <= nn) ? off[node0 + t] : 0;
    }
    if (threadIdx.x == 0) soff[128] = off[node0 + nn];
    __syncthreads();

    int base = soff[0], end = soff[nn];
    for (int t = base + threadIdx.x; t < end; t += 256) {
        unsigned ent = e[t];
        int slot = ent >> 17;
        int oth = (int)(ent & 0x1FFFF);
        int r = atomicAdd(&rk[slot], 1);
        by[soff[slot] + r] = oth;
    }
}

// ---------------------------------------------------------------------------
// CSR mean-aggregate (R4-verified), edge loop now ILP-8.
// ---------------------------------------------------------------------------
__global__ __launch_bounds__(256) void agg_gather(
    const float* __restrict__ X, const int* __restrict__ off_col,
    const int* __restrict__ by_col, float* __restrict__ agg, int n)
{
    int lane = threadIdx.x & 63;
    int node = (blockIdx.x * blockDim.x + threadIdx.x) >> 6;
    if (node >= n) return;
    int s0 = off_col[node], s1 = off_col[node + 1];
    float acc = 0.f;
    for (int base = s0; base < s1; base += 64) {
        int m = s1 - base;
        if (m > 64) m = 64;
        int idx = (lane < m) ? by_col[base + lane] : 0;
        int j = 0;
        for (; j + 8 <= m; j += 8) {
            int r0 = __shfl(idx, j),     r1 = __shfl(idx, j + 1);
            int r2 = __shfl(idx, j + 2), r3 = __shfl(idx, j + 3);
            int r4 = __shfl(idx, j + 4), r5 = __shfl(idx, j + 5);
            int r6 = __shfl(idx, j + 6), r7 = __shfl(idx, j + 7);
            float v0 = X[((size_t)r0 << 6) + lane];
            float v1 = X[((size_t)r1 << 6) + lane];
            float v2 = X[((size_t)r2 << 6) + lane];
            float v3 = X[((size_t)r3 << 6) + lane];
            float v4 = X[((size_t)r4 << 6) + lane];
            float v5 = X[((size_t)r5 << 6) + lane];
            float v6 = X[((size_t)r6 << 6) + lane];
            float v7 = X[((size_t)r7 << 6) + lane];
            acc += ((v0 + v1) + (v2 + v3)) + ((v4 + v5) + (v6 + v7));
        }
        for (; j < m; ++j) {
            int r = __shfl(idx, j);
            acc += X[((size_t)r << 6) + lane];
        }
    }
    float deg = (float)(s1 - s0);
    agg[((size_t)node << 6) + lane] = acc / fmaxf(deg, 1.f);
}

// ---------------------------------------------------------------------------
// pack_w + linear_mfma: unchanged from R4 (verified, absmax 0.0039).
// ---------------------------------------------------------------------------
__global__ __launch_bounds__(256) void pack_w(
    const float* __restrict__ Wl, const float* __restrict__ Wr,
    unsigned short* __restrict__ wpack)
{
    for (int c = threadIdx.x; c < 8192; c += 256) {
        int j = c & 7;
        int lane = (c >> 3) & 63;
        int tile = (c >> 9) & 7;
        int mat = c >> 12;
        int kc = tile >> 2;
        int nt = tile & 3;
        int krow = (lane >> 4) * 8 + j + kc * 32;
        int col = (lane & 15) + nt * 16;
        const float* W = mat ? Wr : Wl;
        float v = W[krow * 64 + col];
        unsigned short hi = f2bf(v);
        unsigned short lo = f2bf(v - bf2f(hi));
        int base = mat * 8192 + tile * 512 + lane * 8 + j;
        wpack[base] = hi;
        wpack[base + 4096] = lo;
    }
}

__global__ __launch_bounds__(256) void linear_mfma(
    const float* __restrict__ X, const float* __restrict__ agg,
    const unsigned short* __restrict__ wpack, const float* __restrict__ b,
    float* __restrict__ h, int n, int ngroups)
{
    int lane = threadIdx.x & 63;
    int g = (blockIdx.x * blockDim.x + threadIdx.x) >> 6;
    if (g >= ngroups) return;
    int quad = lane >> 4;
    int l15 = lane & 15;

    frag_ab wf[2][2][2][4];
    #pragma unroll
    for (int mat = 0; mat < 2; ++mat)
        #pragma unroll
        for (int hf = 0; hf < 2; ++hf)
            #pragma unroll
            for (int kc = 0; kc < 2; ++kc)
                #pragma unroll
                for (int nt = 0; nt < 4; ++nt) {
                    const unsigned short* p =
                        wpack + mat * 8192 + hf * 4096 + (kc * 4 + nt) * 512 + lane * 8;
                    wf[mat][hf][kc][nt] = *(const frag_ab*)p;
                }

    frag_cd acc[4];
    #pragma unroll
    for (int nt = 0; nt < 4; ++nt) acc[nt] = (frag_cd){0.f, 0.f, 0.f, 0.f};

    int mrow = g * 16 + l15;
    if (mrow >= n) mrow = n - 1;
    const float* arow = agg + ((size_t)mrow << 6) + quad * 8;
    const float* xrow = X + ((size_t)mrow << 6) + quad * 8;

    #pragma unroll
    for (int kc = 0; kc < 2; ++kc) {
        float av[8], xv[8];
        #pragma unroll
        for (int t = 0; t < 2; ++t) {
            float4 a4 = *(const float4*)(arow + kc * 32 + t * 4);
            float4 x4 = *(const float4*)(xrow + kc * 32 + t * 4);
            av[t * 4 + 0] = a4.x; av[t * 4 + 1] = a4.y;
            av[t * 4 + 2] = a4.z; av[t * 4 + 3] = a4.w;
            xv[t * 4 + 0] = x4.x; xv[t * 4 + 1] = x4.y;
            xv[t * 4 + 2] = x4.z; xv[t * 4 + 3] = x4.w;
        }
        frag_ab ah, al, xh, xl;
        #pragma unroll
        for (int j = 0; j < 8; ++j) {
            unsigned short hb = f2bf(av[j]);
            ah[j] = (short)hb;
            al[j] = (short)f2bf(av[j] - bf2f(hb));
            unsigned short xb = f2bf(xv[j]);
            xh[j] = (short)xb;
            xl[j] = (short)f2bf(xv[j] - bf2f(xb));
        }
        #pragma unroll
        for (int nt = 0; nt < 4; ++nt) {
            acc[nt] = __builtin_amdgcn_mfma_f32_16x16x32_bf16(ah, wf[0][0][kc][nt], acc[nt], 0, 0, 0);
            acc[nt] = __builtin_amdgcn_mfma_f32_16x16x32_bf16(ah, wf[0][1][kc][nt], acc[nt], 0, 0, 0);
            acc[nt] = __builtin_amdgcn_mfma_f32_16x16x32_bf16(al, wf[0][0][kc][nt], acc[nt], 0, 0, 0);
            acc[nt] = __builtin_amdgcn_mfma_f32_16x16x32_bf16(xh, wf[1][0][kc][nt], acc[nt], 0, 0, 0);
            acc[nt] = __builtin_amdgcn_mfma_f32_16x16x32_bf16(xh, wf[1][1][kc][nt], acc[nt], 0, 0, 0);
            acc[nt] = __builtin_amdgcn_mfma_f32_16x16x32_bf16(xl, wf[1][0][kc][nt], acc[nt], 0, 0, 0);
        }
    }

    #pragma unroll
    for (int nt = 0; nt < 4; ++nt) {
        float bj = b[l15 + nt * 16];
        #pragma unroll
        for (int r = 0; r < 4; ++r) {
            int row = quad * 4 + r;
            int node = g * 16 + row;
            if (node < n) {
                float v = acc[nt][r] + bj;
                h[((size_t)node << 6) + l15 + nt * 16] = fmaxf(v, 0.f);
            }
        }
    }
}

// ---------------------------------------------------------------------------
// Gate (R4-verified), edge loop now ILP-8.
// ---------------------------------------------------------------------------
__global__ __launch_bounds__(256) void gate_kernel(
    const float* __restrict__ h, const int* __restrict__ off_row,
    const int* __restrict__ by_row, float* __restrict__ out, int n)
{
    int lane = threadIdx.x & 63;
    int u = (blockIdx.x * blockDim.x + threadIdx.x) >> 6;
    if (u >= n) return;
    int s0 = off_row[u], s1 = off_row[u + 1];
    float hu = h[((size_t)u << 6) + lane];
    float acc = 0.f;
    for (int base = s0; base < s1; base += 64) {
        int m = s1 - base;
        if (m > 64) m = 64;
        int idx = (lane < m) ? by_row[base + lane] : 0;
        int j = 0;
        for (; j + 8 <= m; j += 8) {
            int c0 = __shfl(idx, j),     c1 = __shfl(idx, j + 1);
            int c2 = __shfl(idx, j + 2), c3 = __shfl(idx, j + 3);
            int c4 = __shfl(idx, j + 4), c5 = __shfl(idx, j + 5);
            int c6 = __shfl(idx, j + 6), c7 = __shfl(idx, j + 7);
            float v0 = h[((size_t)c0 << 6) + lane];
            float v1 = h[((size_t)c1 << 6) + lane];
            float v2 = h[((size_t)c2 << 6) + lane];
            float v3 = h[((size_t)c3 << 6) + lane];
            float v4 = h[((size_t)c4 << 6) + lane];
            float v5 = h[((size_t)c5 << 6) + lane];
            float v6 = h[((size_t)c6 << 6) + lane];
            float v7 = h[((size_t)c7 << 6) + lane];
            float d0 = hu - v0, d1 = hu - v1, d2 = hu - v2, d3 = hu - v3;
            float d4 = hu - v4, d5 = hu - v5, d6 = hu - v6, d7 = hu - v7;
            acc += ((d0 * d0 + d1 * d1) + (d2 * d2 + d3 * d3)) +
                   ((d4 * d4 + d5 * d5) + (d6 * d6 + d7 * d7));
        }
        for (; j < m; ++j) {
            int c = __shfl(idx, j);
            float d = hu - h[((size_t)c << 6) + lane];
            acc += d * d;
        }
    }
    float deg = (float)(s1 - s0);
    out[((size_t)u << 6) + lane] = tanhf(acc / fmaxf(deg, 1.f));
}

extern "C" void kernel_launch(void* const* d_in, const int* in_sizes, int n_in,
                              void* d_out, int out_size, void* d_ws, size_t ws_size,
                              hipStream_t stream) {
    const float* X  = (const float*)d_in[0];
    const int*   ei = (const int*)d_in[1];
    const float* Wl = (const float*)d_in[2];
    const float* Wr = (const float*)d_in[3];
    const float* b  = (const float*)d_in[4];
    float* out = (float*)d_out;

    int n = in_sizes[0] / D;
    int n_edges = in_sizes[1] / 2;
    int nbs = (n + 1023) / 1024;   // node-scan blocks (98)
    int nbk = (n + 127) >> 7;      // 128-node buckets (782)

    // ws layout (~73 MB)
    float* agg = (float*)d_ws;                                       // n*64
    float* h   = agg + (size_t)n * D;                                // n*64
    unsigned short* wpack = (unsigned short*)(h + (size_t)n * D);    // 16384
    int* w = (int*)(wpack + 16384);
    int* deg_col  = w;                     // n
    int* deg_row  = deg_col + n;           // n
    int* off_col  = deg_row + n;           // n+1
    int* off_row  = off_col + (n + 1);     // n+1
    int* tot_col  = off_row + (n + 1);     // nbs
    int* tot_row  = tot_col + nbs;         // nbs
    int* gcur_col = tot_row + nbs;         // nbk
    int* gcur_row = gcur_col + nbk;        // nbk
    unsigned* ecol = (unsigned*)(gcur_row + nbk);   // n_edges
    unsigned* erow = ecol + n_edges;                // n_edges
    int* by_col = (int*)(erow + n_edges);           // n_edges
    int* by_row = by_col + n_edges;                 // n_edges

    hipMemsetAsync(deg_col, 0, (size_t)2 * n * sizeof(int), stream);

    int eb = (n_edges + 255) / 256;
    hist_deg<<<eb, 256, 0, stream>>>(ei, deg_col, deg_row, n_edges);
    scan_blocks<<<2 * nbs, 1024, 0, stream>>>(deg_col, off_col, tot_col,
                                              deg_row, off_row, tot_row, n, nbs);
    scan_totals<<<2, 64, 0, stream>>>(tot_col, off_col, tot_row, off_row, nbs, n);
    add_offsets<<<2 * nbs, 1024, 0, stream>>>(off_col, tot_col, off_row,
                                              tot_row, n, nbs);
    init_gcur<<<(nbk + 255) / 256, 256, 0, stream>>>(off_col, off_row,
                                                     gcur_col, gcur_row, nbk);
    multisplit<<<(n_edges + CHUNK - 1) / CHUNK, MS_T, 0, stream>>>(
        ei, n_edges, nbk, gcur_col, gcur_row, ecol, erow);
    bucket_to_csr<<<2 * nbk, 256, 0, stream>>>(ecol, erow, off_col, off_row,
                                               by_col, by_row, n, nbk);

    pack_w<<<1, 256, 0, stream>>>(Wl, Wr, wpack);

    agg_gather<<<(n + 3) / 4, 256, 0, stream>>>(X, off_col, by_col, agg, n);

    int ngroups = (n + 15) / 16;
    linear_mfma<<<(ngroups + 3) / 4, 256, 0, stream>>>(X, agg, wpack, b, h, n,
                                                       ngroups);

    gate_kernel<<<(n + 3) / 4, 256, 0, stream>>>(h, off_row, by_row, out, n);
}

// Round 7
// 300.362 us; speedup vs baseline: 6.2719x; 1.2515x over previous
//
#include <hip/hip_runtime.h>
#include <math.h>

#define D 64
#define CHUNK 4096
#define MS_T 256
#define EPT 16          // CHUNK / MS_T
#define MAXNB 800       // >= nbk = ceil(n/128); n=100000 -> 782

typedef __attribute__((ext_vector_type(8))) short frag_ab;
typedef __attribute__((ext_vector_type(4))) float frag_cd;

__device__ __forceinline__ unsigned short f2bf(float f) {
    unsigned u = __float_as_uint(f);
    u += 0x7FFFu + ((u >> 16) & 1u);
    return (unsigned short)(u >> 16);
}
__device__ __forceinline__ float bf2f(unsigned short s) {
    return __uint_as_float(((unsigned)s) << 16);
}

// ---------------------------------------------------------------------------
// Per-chunk LDS histogram over 128-node buckets -> few global atomics on a
// 6KB-hot region (replaces hist_deg's 2.5M random atomics / 78MB writes).
// ---------------------------------------------------------------------------
__global__ __launch_bounds__(MS_T) void bucket_hist(
    const int* __restrict__ ei, int n_edges, int nbk,
    int* __restrict__ bc_col, int* __restrict__ bc_row)
{
    __shared__ int scol[MAXNB];
    __shared__ int srow[MAXNB];
    for (int t = threadIdx.x; t < nbk; t += MS_T) {
        scol[t] = 0;
        srow[t] = 0;
    }
    __syncthreads();

    int base = blockIdx.x * CHUNK;
    int cc = n_edges - base;
    if (cc > CHUNK) cc = CHUNK;
    #pragma unroll
    for (int k = 0; k < EPT; ++k) {
        int i = threadIdx.x + k * MS_T;
        if (i < cc) {
            int r = ei[base + i];
            int c = ei[n_edges + base + i];
            atomicAdd(&srow[r >> 7], 1);   // LDS scalar atomics: cheap
            atomicAdd(&scol[c >> 7], 1);
        }
    }
    __syncthreads();
    for (int t = threadIdx.x; t < nbk; t += MS_T) {
        if (scol[t]) atomicAdd(&bc_col[t], scol[t]);
        if (srow[t]) atomicAdd(&bc_row[t], srow[t]);
    }
}

// ---------------------------------------------------------------------------
// scan 782 bucket counts -> bucket bases; init multisplit cursors. One block.
// ---------------------------------------------------------------------------
__global__ __launch_bounds__(64) void bucket_scan(
    const int* __restrict__ bc_col, const int* __restrict__ bc_row,
    int* __restrict__ bbase_col, int* __restrict__ bbase_row,
    int* __restrict__ gcur_col, int* __restrict__ gcur_row, int nbk)
{
    int lane = threadIdx.x;
    for (int w = 0; w < 2; ++w) {
        const int* bc = w ? bc_row : bc_col;
        int* bb = w ? bbase_row : bbase_col;
        int* gc = w ? gcur_row : gcur_col;
        int carry = 0;
        for (int b0 = 0; b0 < nbk; b0 += 64) {
            int v = (b0 + lane < nbk) ? bc[b0 + lane] : 0;
            int x = v;
            #pragma unroll
            for (int o = 1; o < 64; o <<= 1) {
                int u = __shfl_up(x, o);
                if (lane >= o) x += u;
            }
            if (b0 + lane < nbk) {
                int e = carry + x - v;
                bb[b0 + lane] = e;
                gc[b0 + lane] = e;
            }
            carry += __shfl(x, 63);
        }
    }
}

// ---------------------------------------------------------------------------
// Multisplit (R6-verified): group edges into 128-node buckets, both orders.
// Entry = ((key & 127) << 17) | other.
// ---------------------------------------------------------------------------
__global__ __launch_bounds__(MS_T) void multisplit(
    const int* __restrict__ ei, int n_edges, int nbk,
    int* __restrict__ gcur_col, int* __restrict__ gcur_row,
    unsigned* __restrict__ ecol, unsigned* __restrict__ erow)
{
    __shared__ unsigned stage[CHUNK];
    __shared__ unsigned short sbk[CHUNK];
    __shared__ int cnt[MAXNB];
    __shared__ int off[MAXNB + 1];
    __shared__ int gb[MAXNB];

    int base = blockIdx.x * CHUNK;
    int cc = n_edges - base;
    if (cc > CHUNK) cc = CHUNK;

    int r[EPT], c[EPT];
    #pragma unroll
    for (int k = 0; k < EPT; ++k) {
        int i = threadIdx.x + k * MS_T;
        if (i < cc) {
            r[k] = ei[base + i];
            c[k] = ei[n_edges + base + i];
        }
    }

    for (int ord = 0; ord < 2; ++ord) {
        int* gcur = ord ? gcur_row : gcur_col;
        unsigned* eout = ord ? erow : ecol;

        for (int t = threadIdx.x; t < nbk; t += MS_T) cnt[t] = 0;
        __syncthreads();

        int rk[EPT], bk[EPT];
        #pragma unroll
        for (int k = 0; k < EPT; ++k) {
            int i = threadIdx.x + k * MS_T;
            if (i < cc) {
                int key = ord ? r[k] : c[k];
                bk[k] = key >> 7;
                rk[k] = atomicAdd(&cnt[bk[k]], 1);
            }
        }
        __syncthreads();

        if (threadIdx.x < 64) {           // wave 0: scan + global reservation
            int lane = threadIdx.x;
            int carry = 0;
            for (int b0 = 0; b0 < nbk; b0 += 64) {
                int v = (b0 + lane < nbk) ? cnt[b0 + lane] : 0;
                int x = v;
                #pragma unroll
                for (int o = 1; o < 64; o <<= 1) {
                    int u = __shfl_up(x, o);
                    if (lane >= o) x += u;
                }
                if (b0 + lane < nbk) {
                    off[b0 + lane] = carry + x - v;
                    gb[b0 + lane] = v ? atomicAdd(&gcur[b0 + lane], v) : 0;
                }
                carry += __shfl(x, 63);
            }
        }
        __syncthreads();

        #pragma unroll
        for (int k = 0; k < EPT; ++k) {
            int i = threadIdx.x + k * MS_T;
            if (i < cc) {
                int key = ord ? r[k] : c[k];
                int oth = ord ? c[k] : r[k];
                int p = off[bk[k]] + rk[k];
                stage[p] = ((unsigned)(key & 127) << 17) | (unsigned)oth;
                sbk[p] = (unsigned short)bk[k];
            }
        }
        __syncthreads();

        for (int t = threadIdx.x; t < cc; t += MS_T) {
            int bb = sbk[t];
            eout[gb[bb] + (t - off[bb])] = stage[t];
        }
        __syncthreads();
    }
}

// ---------------------------------------------------------------------------
// csr_build: one block per (bucket, ordering). LDS-histogram the 128 node
// slots, local scan -> global off[] (coalesced) ; scatter entries into by[]
// within the bucket's contiguous window (write amp ~1). Replaces hist_deg +
// node scan + bucket_to_csr. Degree = off[u+1]-off[u] downstream.
// ---------------------------------------------------------------------------
__global__ __launch_bounds__(256) void csr_build(
    const unsigned* __restrict__ ecol, const unsigned* __restrict__ erow,
    const int* __restrict__ bbase_col, const int* __restrict__ bbase_row,
    const int* __restrict__ bc_col, const int* __restrict__ bc_row,
    int* __restrict__ off_col, int* __restrict__ off_row,
    int* __restrict__ by_col, int* __restrict__ by_row, int n, int nbk)
{
    __shared__ int scnt[128];
    __shared__ int soff[129];
    bool isRow = blockIdx.x >= (unsigned)nbk;
    int b = isRow ? (blockIdx.x - nbk) : blockIdx.x;
    const unsigned* e = isRow ? erow : ecol;
    int base = (isRow ? bbase_row : bbase_col)[b];
    int ec = (isRow ? bc_row : bc_col)[b];
    int* off_g = isRow ? off_row : off_col;
    int* by = isRow ? by_row : by_col;

    int node0 = b << 7;
    int nn = n - node0;
    if (nn > 128) nn = 128;

    if (threadIdx.x < 128) scnt[threadIdx.x] = 0;
    __syncthreads();

    for (int t = threadIdx.x; t < ec; t += 256)
        atomicAdd(&scnt[e[base + t] >> 17], 1);
    __syncthreads();

    if (threadIdx.x < 64) {               // wave 0: scan 128 slots
        int lane = threadIdx.x;
        int carry = 0;
        #pragma unroll
        for (int b0 = 0; b0 < 128; b0 += 64) {
            int v = scnt[b0 + lane];
            int x = v;
            #pragma unroll
            for (int o = 1; o < 64; o <<= 1) {
                int u = __shfl_up(x, o);
                if (lane >= o) x += u;
            }
            soff[b0 + lane] = carry + x - v;
            carry += __shfl(x, 63);
        }
        if (lane == 63) soff[128] = carry;
    }
    __syncthreads();

    if (threadIdx.x < 128) {
        if (threadIdx.x < nn) off_g[node0 + threadIdx.x] = base + soff[threadIdx.x];
        scnt[threadIdx.x] = 0;            // reset for rank pass
    }
    if (threadIdx.x == 0 && node0 + nn == n) off_g[n] = base + soff[nn];
    __syncthreads();

    for (int t = threadIdx.x; t < ec; t += 256) {
        unsigned ent = e[base + t];
        int slot = ent >> 17;
        int r = atomicAdd(&scnt[slot], 1);
        by[base + soff[slot] + r] = (int)(ent & 0x1FFFF);
    }
}

// ---------------------------------------------------------------------------
// CSR mean-aggregate (R4/R6-verified), ILP-8 gathers. deg from off.
// ---------------------------------------------------------------------------
__global__ __launch_bounds__(256) void agg_gather(
    const float* __restrict__ X, const int* __restrict__ off_col,
    const int* __restrict__ by_col, float* __restrict__ agg, int n)
{
    int lane = threadIdx.x & 63;
    int node = (blockIdx.x * blockDim.x + threadIdx.x) >> 6;
    if (node >= n) return;
    int s0 = off_col[node], s1 = off_col[node + 1];
    float acc = 0.f;
    for (int base = s0; base < s1; base += 64) {
        int m = s1 - base;
        if (m > 64) m = 64;
        int idx = (lane < m) ? by_col[base + lane] : 0;
        int j = 0;
        for (; j + 8 <= m; j += 8) {
            int r0 = __shfl(idx, j),     r1 = __shfl(idx, j + 1);
            int r2 = __shfl(idx, j + 2), r3 = __shfl(idx, j + 3);
            int r4 = __shfl(idx, j + 4), r5 = __shfl(idx, j + 5);
            int r6 = __shfl(idx, j + 6), r7 = __shfl(idx, j + 7);
            float v0 = X[((size_t)r0 << 6) + lane];
            float v1 = X[((size_t)r1 << 6) + lane];
            float v2 = X[((size_t)r2 << 6) + lane];
            float v3 = X[((size_t)r3 << 6) + lane];
            float v4 = X[((size_t)r4 << 6) + lane];
            float v5 = X[((size_t)r5 << 6) + lane];
            float v6 = X[((size_t)r6 << 6) + lane];
            float v7 = X[((size_t)r7 << 6) + lane];
            acc += ((v0 + v1) + (v2 + v3)) + ((v4 + v5) + (v6 + v7));
        }
        for (; j < m; ++j) {
            int r = __shfl(idx, j);
            acc += X[((size_t)r << 6) + lane];
        }
    }
    float deg = (float)(s1 - s0);
    agg[((size_t)node << 6) + lane] = acc / fmaxf(deg, 1.f);
}

// ---------------------------------------------------------------------------
// pack_w + linear_mfma (R4-verified, absmax 0.0039).
// ---------------------------------------------------------------------------
__global__ __launch_bounds__(256) void pack_w(
    const float* __restrict__ Wl, const float* __restrict__ Wr,
    unsigned short* __restrict__ wpack)
{
    for (int c = threadIdx.x; c < 8192; c += 256) {
        int j = c & 7;
        int lane = (c >> 3) & 63;
        int tile = (c >> 9) & 7;
        int mat = c >> 12;
        int kc = tile >> 2;
        int nt = tile & 3;
        int krow = (lane >> 4) * 8 + j + kc * 32;
        int col = (lane & 15) + nt * 16;
        const float* W = mat ? Wr : Wl;
        float v = W[krow * 64 + col];
        unsigned short hi = f2bf(v);
        unsigned short lo = f2bf(v - bf2f(hi));
        int base = mat * 8192 + tile * 512 + lane * 8 + j;
        wpack[base] = hi;
        wpack[base + 4096] = lo;
    }
}

__global__ __launch_bounds__(256) void linear_mfma(
    const float* __restrict__ X, const float* __restrict__ agg,
    const unsigned short* __restrict__ wpack, const float* __restrict__ b,
    float* __restrict__ h, int n, int ngroups)
{
    int lane = threadIdx.x & 63;
    int g = (blockIdx.x * blockDim.x + threadIdx.x) >> 6;
    if (g >= ngroups) return;
    int quad = lane >> 4;
    int l15 = lane & 15;

    frag_ab wf[2][2][2][4];
    #pragma unroll
    for (int mat = 0; mat < 2; ++mat)
        #pragma unroll
        for (int hf = 0; hf < 2; ++hf)
            #pragma unroll
            for (int kc = 0; kc < 2; ++kc)
                #pragma unroll
                for (int nt = 0; nt < 4; ++nt) {
                    const unsigned short* p =
                        wpack + mat * 8192 + hf * 4096 + (kc * 4 + nt) * 512 + lane * 8;
                    wf[mat][hf][kc][nt] = *(const frag_ab*)p;
                }

    frag_cd acc[4];
    #pragma unroll
    for (int nt = 0; nt < 4; ++nt) acc[nt] = (frag_cd){0.f, 0.f, 0.f, 0.f};

    int mrow = g * 16 + l15;
    if (mrow >= n) mrow = n - 1;
    const float* arow = agg + ((size_t)mrow << 6) + quad * 8;
    const float* xrow = X + ((size_t)mrow << 6) + quad * 8;

    #pragma unroll
    for (int kc = 0; kc < 2; ++kc) {
        float av[8], xv[8];
        #pragma unroll
        for (int t = 0; t < 2; ++t) {
            float4 a4 = *(const float4*)(arow + kc * 32 + t * 4);
            float4 x4 = *(const float4*)(xrow + kc * 32 + t * 4);
            av[t * 4 + 0] = a4.x; av[t * 4 + 1] = a4.y;
            av[t * 4 + 2] = a4.z; av[t * 4 + 3] = a4.w;
            xv[t * 4 + 0] = x4.x; xv[t * 4 + 1] = x4.y;
            xv[t * 4 + 2] = x4.z; xv[t * 4 + 3] = x4.w;
        }
        frag_ab ah, al, xh, xl;
        #pragma unroll
        for (int j = 0; j < 8; ++j) {
            unsigned short hb = f2bf(av[j]);
            ah[j] = (short)hb;
            al[j] = (short)f2bf(av[j] - bf2f(hb));
            unsigned short xb = f2bf(xv[j]);
            xh[j] = (short)xb;
            xl[j] = (short)f2bf(xv[j] - bf2f(xb));
        }
        #pragma unroll
        for (int nt = 0; nt < 4; ++nt) {
            acc[nt] = __builtin_amdgcn_mfma_f32_16x16x32_bf16(ah, wf[0][0][kc][nt], acc[nt], 0, 0, 0);
            acc[nt] = __builtin_amdgcn_mfma_f32_16x16x32_bf16(ah, wf[0][1][kc][nt], acc[nt], 0, 0, 0);
            acc[nt] = __builtin_amdgcn_mfma_f32_16x16x32_bf16(al, wf[0][0][kc][nt], acc[nt], 0, 0, 0);
            acc[nt] = __builtin_amdgcn_mfma_f32_16x16x32_bf16(xh, wf[1][0][kc][nt], acc[nt], 0, 0, 0);
            acc[nt] = __builtin_amdgcn_mfma_f32_16x16x32_bf16(xh, wf[1][1][kc][nt], acc[nt], 0, 0, 0);
            acc[nt] = __builtin_amdgcn_mfma_f32_16x16x32_bf16(xl, wf[1][0][kc][nt], acc[nt], 0, 0, 0);
        }
    }

    #pragma unroll
    for (int nt = 0; nt < 4; ++nt) {
        float bj = b[l15 + nt * 16];
        #pragma unroll
        for (int r = 0; r < 4; ++r) {
            int row = quad * 4 + r;
            int node = g * 16 + row;
            if (node < n) {
                float v = acc[nt][r] + bj;
                h[((size_t)node << 6) + l15 + nt * 16] = fmaxf(v, 0.f);
            }
        }
    }
}

// ---------------------------------------------------------------------------
// Gate (R4/R6-verified), ILP-8. deg from off.
// ---------------------------------------------------------------------------
__global__ __launch_bounds__(256) void gate_kernel(
    const float* __restrict__ h, const int* __restrict__ off_row,
    const int* __restrict__ by_row, float* __restrict__ out, int n)
{
    int lane = threadIdx.x & 63;
    int u = (blockIdx.x * blockDim.x + threadIdx.x) >> 6;
    if (u >= n) return;
    int s0 = off_row[u], s1 = off_row[u + 1];
    float hu = h[((size_t)u << 6) + lane];
    float acc = 0.f;
    for (int base = s0; base < s1; base += 64) {
        int m = s1 - base;
        if (m > 64) m = 64;
        int idx = (lane < m) ? by_row[base + lane] : 0;
        int j = 0;
        for (; j + 8 <= m; j += 8) {
            int c0 = __shfl(idx, j),     c1 = __shfl(idx, j + 1);
            int c2 = __shfl(idx, j + 2), c3 = __shfl(idx, j + 3);
            int c4 = __shfl(idx, j + 4), c5 = __shfl(idx, j + 5);
            int c6 = __shfl(idx, j + 6), c7 = __shfl(idx, j + 7);
            float v0 = h[((size_t)c0 << 6) + lane];
            float v1 = h[((size_t)c1 << 6) + lane];
            float v2 = h[((size_t)c2 << 6) + lane];
            float v3 = h[((size_t)c3 << 6) + lane];
            float v4 = h[((size_t)c4 << 6) + lane];
            float v5 = h[((size_t)c5 << 6) + lane];
            float v6 = h[((size_t)c6 << 6) + lane];
            float v7 = h[((size_t)c7 << 6) + lane];
            float d0 = hu - v0, d1 = hu - v1, d2 = hu - v2, d3 = hu - v3;
            float d4 = hu - v4, d5 = hu - v5, d6 = hu - v6, d7 = hu - v7;
            acc += ((d0 * d0 + d1 * d1) + (d2 * d2 + d3 * d3)) +
                   ((d4 * d4 + d5 * d5) + (d6 * d6 + d7 * d7));
        }
        for (; j < m; ++j) {
            int c = __shfl(idx, j);
            float d = hu - h[((size_t)c << 6) + lane];
            acc += d * d;
        }
    }
    float deg = (float)(s1 - s0);
    out[((size_t)u << 6) + lane] = tanhf(acc / fmaxf(deg, 1.f));
}

extern "C" void kernel_launch(void* const* d_in, const int* in_sizes, int n_in,
                              void* d_out, int out_size, void* d_ws, size_t ws_size,
                              hipStream_t stream) {
    const float* X  = (const float*)d_in[0];
    const int*   ei = (const int*)d_in[1];
    const float* Wl = (const float*)d_in[2];
    const float* Wr = (const float*)d_in[3];
    const float* b  = (const float*)d_in[4];
    float* out = (float*)d_out;

    int n = in_sizes[0] / D;
    int n_edges = in_sizes[1] / 2;
    int nbk = (n + 127) >> 7;      // 128-node buckets (782)
    int nchunks = (n_edges + CHUNK - 1) / CHUNK;

    // ws layout (~71 MB)
    float* agg = (float*)d_ws;                                       // n*64
    float* h   = agg + (size_t)n * D;                                // n*64
    unsigned short* wpack = (unsigned short*)(h + (size_t)n * D);    // 16384
    int* w = (int*)(wpack + 16384);
    int* bc_col    = w;                    // nbk
    int* bc_row    = bc_col + nbk;         // nbk
    int* bbase_col = bc_row + nbk;         // nbk
    int* bbase_row = bbase_col + nbk;      // nbk
    int* gcur_col  = bbase_row + nbk;      // nbk
    int* gcur_row  = gcur_col + nbk;       // nbk
    int* off_col   = gcur_row + nbk;       // n+1
    int* off_row   = off_col + (n + 1);    // n+1
    unsigned* ecol = (unsigned*)(off_row + (n + 1));   // n_edges
    unsigned* erow = ecol + n_edges;                   // n_edges
    int* by_col = (int*)(erow + n_edges);              // n_edges
    int* by_row = by_col + n_edges;                    // n_edges

    hipMemsetAsync(bc_col, 0, (size_t)2 * nbk * sizeof(int), stream);

    bucket_hist<<<nchunks, MS_T, 0, stream>>>(ei, n_edges, nbk, bc_col, bc_row);
    bucket_scan<<<1, 64, 0, stream>>>(bc_col, bc_row, bbase_col, bbase_row,
                                      gcur_col, gcur_row, nbk);
    multisplit<<<nchunks, MS_T, 0, stream>>>(ei, n_edges, nbk,
                                             gcur_col, gcur_row, ecol, erow);
    csr_build<<<2 * nbk, 256, 0, stream>>>(ecol, erow, bbase_col, bbase_row,
                                           bc_col, bc_row, off_col, off_row,
                                           by_col, by_row, n, nbk);

    pack_w<<<1, 256, 0, stream>>>(Wl, Wr, wpack);

    agg_gather<<<(n + 3) / 4, 256, 0, stream>>>(X, off_col, by_col, agg, n);

    int ngroups = (n + 15) / 16;
    linear_mfma<<<(ngroups + 3) / 4, 256, 0, stream>>>(X, agg, wpack, b, h, n,
                                                       ngroups);

    gate_kernel<<<(n + 3) / 4, 256, 0, stream>>>(h, off_row, by_row, out, n);
}

// Round 8
// 277.232 us; speedup vs baseline: 6.7952x; 1.0834x over previous
//
#include <hip/hip_runtime.h>
#include <math.h>

#define D 64
#define CHUNK 4096
#define MS_T 256
#define EPT 16          // CHUNK / MS_T
#define MAXNB 800       // >= nbk = ceil(n/128); n=100000 -> 782

typedef __attribute__((ext_vector_type(8))) short frag_ab;
typedef __attribute__((ext_vector_type(4))) float frag_cd;

__device__ __forceinline__ unsigned short f2bf(float f) {
    unsigned u = __float_as_uint(f);
    u += 0x7FFFu + ((u >> 16) & 1u);
    return (unsigned short)(u >> 16);
}
__device__ __forceinline__ float bf2f(unsigned short s) {
    return __uint_as_float(((unsigned)s) << 16);
}

// ---------------------------------------------------------------------------
// X (fp32) -> packed bf16 pairs (halves gather bytes in agg_gather)
// ---------------------------------------------------------------------------
__global__ __launch_bounds__(256) void convert_x(
    const float* __restrict__ X, unsigned* __restrict__ xb, int total)
{
    int i = blockIdx.x * blockDim.x + threadIdx.x;
    if (i >= total) return;
    float2 v = ((const float2*)X)[i];
    xb[i] = (unsigned)f2bf(v.x) | ((unsigned)f2bf(v.y) << 16);
}

// ---------------------------------------------------------------------------
// Per-chunk LDS histogram over 128-node buckets (R7-verified)
// ---------------------------------------------------------------------------
__global__ __launch_bounds__(MS_T) void bucket_hist(
    const int* __restrict__ ei, int n_edges, int nbk,
    int* __restrict__ bc_col, int* __restrict__ bc_row)
{
    __shared__ int scol[MAXNB];
    __shared__ int srow[MAXNB];
    for (int t = threadIdx.x; t < nbk; t += MS_T) {
        scol[t] = 0;
        srow[t] = 0;
    }
    __syncthreads();

    int base = blockIdx.x * CHUNK;
    int cc = n_edges - base;
    if (cc > CHUNK) cc = CHUNK;
    #pragma unroll
    for (int k = 0; k < EPT; ++k) {
        int i = threadIdx.x + k * MS_T;
        if (i < cc) {
            int r = ei[base + i];
            int c = ei[n_edges + base + i];
            atomicAdd(&srow[r >> 7], 1);
            atomicAdd(&scol[c >> 7], 1);
        }
    }
    __syncthreads();
    for (int t = threadIdx.x; t < nbk; t += MS_T) {
        if (scol[t]) atomicAdd(&bc_col[t], scol[t]);
        if (srow[t]) atomicAdd(&bc_row[t], srow[t]);
    }
}

// ---------------------------------------------------------------------------
// scan 782 bucket counts -> bases; init cursors (R7-verified)
// ---------------------------------------------------------------------------
__global__ __launch_bounds__(64) void bucket_scan(
    const int* __restrict__ bc_col, const int* __restrict__ bc_row,
    int* __restrict__ bbase_col, int* __restrict__ bbase_row,
    int* __restrict__ gcur_col, int* __restrict__ gcur_row, int nbk)
{
    int lane = threadIdx.x;
    for (int w = 0; w < 2; ++w) {
        const int* bc = w ? bc_row : bc_col;
        int* bb = w ? bbase_row : bbase_col;
        int* gc = w ? gcur_row : gcur_col;
        int carry = 0;
        for (int b0 = 0; b0 < nbk; b0 += 64) {
            int v = (b0 + lane < nbk) ? bc[b0 + lane] : 0;
            int x = v;
            #pragma unroll
            for (int o = 1; o < 64; o <<= 1) {
                int u = __shfl_up(x, o);
                if (lane >= o) x += u;
            }
            if (b0 + lane < nbk) {
                int e = carry + x - v;
                bb[b0 + lane] = e;
                gc[b0 + lane] = e;
            }
            carry += __shfl(x, 63);
        }
    }
}

// ---------------------------------------------------------------------------
// Multisplit (R6-verified): group edges into 128-node buckets, both orders.
// ---------------------------------------------------------------------------
__global__ __launch_bounds__(MS_T) void multisplit(
    const int* __restrict__ ei, int n_edges, int nbk,
    int* __restrict__ gcur_col, int* __restrict__ gcur_row,
    unsigned* __restrict__ ecol, unsigned* __restrict__ erow)
{
    __shared__ unsigned stage[CHUNK];
    __shared__ unsigned short sbk[CHUNK];
    __shared__ int cnt[MAXNB];
    __shared__ int off[MAXNB + 1];
    __shared__ int gb[MAXNB];

    int base = blockIdx.x * CHUNK;
    int cc = n_edges - base;
    if (cc > CHUNK) cc = CHUNK;

    int r[EPT], c[EPT];
    #pragma unroll
    for (int k = 0; k < EPT; ++k) {
        int i = threadIdx.x + k * MS_T;
        if (i < cc) {
            r[k] = ei[base + i];
            c[k] = ei[n_edges + base + i];
        }
    }

    for (int ord = 0; ord < 2; ++ord) {
        int* gcur = ord ? gcur_row : gcur_col;
        unsigned* eout = ord ? erow : ecol;

        for (int t = threadIdx.x; t < nbk; t += MS_T) cnt[t] = 0;
        __syncthreads();

        int rk[EPT], bk[EPT];
        #pragma unroll
        for (int k = 0; k < EPT; ++k) {
            int i = threadIdx.x + k * MS_T;
            if (i < cc) {
                int key = ord ? r[k] : c[k];
                bk[k] = key >> 7;
                rk[k] = atomicAdd(&cnt[bk[k]], 1);
            }
        }
        __syncthreads();

        if (threadIdx.x < 64) {
            int lane = threadIdx.x;
            int carry = 0;
            for (int b0 = 0; b0 < nbk; b0 += 64) {
                int v = (b0 + lane < nbk) ? cnt[b0 + lane] : 0;
                int x = v;
                #pragma unroll
                for (int o = 1; o < 64; o <<= 1) {
                    int u = __shfl_up(x, o);
                    if (lane >= o) x += u;
                }
                if (b0 + lane < nbk) {
                    off[b0 + lane] = carry + x - v;
                    gb[b0 + lane] = v ? atomicAdd(&gcur[b0 + lane], v) : 0;
                }
                carry += __shfl(x, 63);
            }
        }
        __syncthreads();

        #pragma unroll
        for (int k = 0; k < EPT; ++k) {
            int i = threadIdx.x + k * MS_T;
            if (i < cc) {
                int key = ord ? r[k] : c[k];
                int oth = ord ? c[k] : r[k];
                int p = off[bk[k]] + rk[k];
                stage[p] = ((unsigned)(key & 127) << 17) | (unsigned)oth;
                sbk[p] = (unsigned short)bk[k];
            }
        }
        __syncthreads();

        for (int t = threadIdx.x; t < cc; t += MS_T) {
            int bb = sbk[t];
            eout[gb[bb] + (t - off[bb])] = stage[t];
        }
        __syncthreads();
    }
}

// ---------------------------------------------------------------------------
// csr_build (R7-verified): bucket entries -> exact per-node CSR.
// ---------------------------------------------------------------------------
__global__ __launch_bounds__(256) void csr_build(
    const unsigned* __restrict__ ecol, const unsigned* __restrict__ erow,
    const int* __restrict__ bbase_col, const int* __restrict__ bbase_row,
    const int* __restrict__ bc_col, const int* __restrict__ bc_row,
    int* __restrict__ off_col, int* __restrict__ off_row,
    int* __restrict__ by_col, int* __restrict__ by_row, int n, int nbk)
{
    __shared__ int scnt[128];
    __shared__ int soff[129];
    bool isRow = blockIdx.x >= (unsigned)nbk;
    int b = isRow ? (blockIdx.x - nbk) : blockIdx.x;
    const unsigned* e = isRow ? erow : ecol;
    int base = (isRow ? bbase_row : bbase_col)[b];
    int ec = (isRow ? bc_row : bc_col)[b];
    int* off_g = isRow ? off_row : off_col;
    int* by = isRow ? by_row : by_col;

    int node0 = b << 7;
    int nn = n - node0;
    if (nn > 128) nn = 128;

    if (threadIdx.x < 128) scnt[threadIdx.x] = 0;
    __syncthreads();

    for (int t = threadIdx.x; t < ec; t += 256)
        atomicAdd(&scnt[e[base + t] >> 17], 1);
    __syncthreads();

    if (threadIdx.x < 64) {
        int lane = threadIdx.x;
        int carry = 0;
        #pragma unroll
        for (int b0 = 0; b0 < 128; b0 += 64) {
            int v = scnt[b0 + lane];
            int x = v;
            #pragma unroll
            for (int o = 1; o < 64; o <<= 1) {
                int u = __shfl_up(x, o);
                if (lane >= o) x += u;
            }
            soff[b0 + lane] = carry + x - v;
            carry += __shfl(x, 63);
        }
        if (lane == 63) soff[128] = carry;
    }
    __syncthreads();

    if (threadIdx.x < 128) {
        if (threadIdx.x < nn) off_g[node0 + threadIdx.x] = base + soff[threadIdx.x];
        scnt[threadIdx.x] = 0;
    }
    if (threadIdx.x == 0 && node0 + nn == n) off_g[n] = base + soff[nn];
    __syncthreads();

    for (int t = threadIdx.x; t < ec; t += 256) {
        unsigned ent = e[base + t];
        int slot = ent >> 17;
        int r = atomicAdd(&scnt[slot], 1);
        by[base + soff[slot] + r] = (int)(ent & 0x1FFFF);
    }
}

// ---------------------------------------------------------------------------
// CSR mean-aggregate from packed-bf16 xb: 32 lanes/edge -> 2 edges per
// wave-gather, 4 loads in flight; half-wave combine; float2 coalesced store.
// ---------------------------------------------------------------------------
__global__ __launch_bounds__(256) void agg_gather(
    const unsigned* __restrict__ xb, const int* __restrict__ off_col,
    const int* __restrict__ by_col, float* __restrict__ agg, int n)
{
    int lane = threadIdx.x & 63;
    int node = (blockIdx.x * blockDim.x + threadIdx.x) >> 6;
    if (node >= n) return;
    int half = lane >> 5, fl = lane & 31;
    int s0 = off_col[node], s1 = off_col[node + 1];
    float acc0 = 0.f, acc1 = 0.f;
    for (int base = s0; base < s1; base += 64) {
        int m = s1 - base;
        if (m > 64) m = 64;
        int idx = (lane < m) ? by_col[base + lane] : 0;
        for (int j = 0; j < m; j += 8) {          // 4 pairs = 8 edges / iter
            unsigned vv[4];
            bool ok[4];
            #pragma unroll
            for (int p = 0; p < 4; ++p) {
                int jj = j + 2 * p + half;
                int e = __shfl(idx, jj & 63);     // idx=0 for masked lanes: safe addr
                ok[p] = jj < m;
                vv[p] = xb[((size_t)e << 5) + fl];
            }
            #pragma unroll
            for (int p = 0; p < 4; ++p) {
                if (ok[p]) {
                    acc0 += bf2f((unsigned short)(vv[p] & 0xFFFF));
                    acc1 += bf2f((unsigned short)(vv[p] >> 16));
                }
            }
        }
    }
    acc0 += __shfl_xor(acc0, 32);
    acc1 += __shfl_xor(acc1, 32);
    if (lane < 32) {
        float inv = 1.f / fmaxf((float)(s1 - s0), 1.f);
        float2 o;
        o.x = acc0 * inv;
        o.y = acc1 * inv;
        ((float2*)agg)[((size_t)node << 5) + fl] = o;
    }
}

// ---------------------------------------------------------------------------
// pack_w (R4-verified)
// ---------------------------------------------------------------------------
__global__ __launch_bounds__(256) void pack_w(
    const float* __restrict__ Wl, const float* __restrict__ Wr,
    unsigned short* __restrict__ wpack)
{
    for (int c = threadIdx.x; c < 8192; c += 256) {
        int j = c & 7;
        int lane = (c >> 3) & 63;
        int tile = (c >> 9) & 7;
        int mat = c >> 12;
        int kc = tile >> 2;
        int nt = tile & 3;
        int krow = (lane >> 4) * 8 + j + kc * 32;
        int col = (lane & 15) + nt * 16;
        const float* W = mat ? Wr : Wl;
        float v = W[krow * 64 + col];
        unsigned short hi = f2bf(v);
        unsigned short lo = f2bf(v - bf2f(hi));
        int base = mat * 8192 + tile * 512 + lane * 8 + j;
        wpack[base] = hi;
        wpack[base + 4096] = lo;
    }
}

// ---------------------------------------------------------------------------
// linear_mfma (R4-verified math); epilogue now writes packed-bf16 hb only
// (lane-pair packing via __shfl_xor(v,1); drops the 25.6MB fp32 h write).
// ---------------------------------------------------------------------------
__global__ __launch_bounds__(256) void linear_mfma(
    const float* __restrict__ X, const float* __restrict__ agg,
    const unsigned short* __restrict__ wpack, const float* __restrict__ b,
    unsigned* __restrict__ hb, int n, int ngroups)
{
    int lane = threadIdx.x & 63;
    int g = (blockIdx.x * blockDim.x + threadIdx.x) >> 6;
    if (g >= ngroups) return;
    int quad = lane >> 4;
    int l15 = lane & 15;

    frag_ab wf[2][2][2][4];
    #pragma unroll
    for (int mat = 0; mat < 2; ++mat)
        #pragma unroll
        for (int hf = 0; hf < 2; ++hf)
            #pragma unroll
            for (int kc = 0; kc < 2; ++kc)
                #pragma unroll
                for (int nt = 0; nt < 4; ++nt) {
                    const unsigned short* p =
                        wpack + mat * 8192 + hf * 4096 + (kc * 4 + nt) * 512 + lane * 8;
                    wf[mat][hf][kc][nt] = *(const frag_ab*)p;
                }

    frag_cd acc[4];
    #pragma unroll
    for (int nt = 0; nt < 4; ++nt) acc[nt] = (frag_cd){0.f, 0.f, 0.f, 0.f};

    int mrow = g * 16 + l15;
    if (mrow >= n) mrow = n - 1;
    const float* arow = agg + ((size_t)mrow << 6) + quad * 8;
    const float* xrow = X + ((size_t)mrow << 6) + quad * 8;

    #pragma unroll
    for (int kc = 0; kc < 2; ++kc) {
        float av[8], xv[8];
        #pragma unroll
        for (int t = 0; t < 2; ++t) {
            float4 a4 = *(const float4*)(arow + kc * 32 + t * 4);
            float4 x4 = *(const float4*)(xrow + kc * 32 + t * 4);
            av[t * 4 + 0] = a4.x; av[t * 4 + 1] = a4.y;
            av[t * 4 + 2] = a4.z; av[t * 4 + 3] = a4.w;
            xv[t * 4 + 0] = x4.x; xv[t * 4 + 1] = x4.y;
            xv[t * 4 + 2] = x4.z; xv[t * 4 + 3] = x4.w;
        }
        frag_ab ah, al, xh, xl;
        #pragma unroll
        for (int j = 0; j < 8; ++j) {
            unsigned short hbv = f2bf(av[j]);
            ah[j] = (short)hbv;
            al[j] = (short)f2bf(av[j] - bf2f(hbv));
            unsigned short xbv = f2bf(xv[j]);
            xh[j] = (short)xbv;
            xl[j] = (short)f2bf(xv[j] - bf2f(xbv));
        }
        #pragma unroll
        for (int nt = 0; nt < 4; ++nt) {
            acc[nt] = __builtin_amdgcn_mfma_f32_16x16x32_bf16(ah, wf[0][0][kc][nt], acc[nt], 0, 0, 0);
            acc[nt] = __builtin_amdgcn_mfma_f32_16x16x32_bf16(ah, wf[0][1][kc][nt], acc[nt], 0, 0, 0);
            acc[nt] = __builtin_amdgcn_mfma_f32_16x16x32_bf16(al, wf[0][0][kc][nt], acc[nt], 0, 0, 0);
            acc[nt] = __builtin_amdgcn_mfma_f32_16x16x32_bf16(xh, wf[1][0][kc][nt], acc[nt], 0, 0, 0);
            acc[nt] = __builtin_amdgcn_mfma_f32_16x16x32_bf16(xh, wf[1][1][kc][nt], acc[nt], 0, 0, 0);
            acc[nt] = __builtin_amdgcn_mfma_f32_16x16x32_bf16(xl, wf[1][0][kc][nt], acc[nt], 0, 0, 0);
        }
    }

    #pragma unroll
    for (int nt = 0; nt < 4; ++nt) {
        float bj = b[l15 + nt * 16];
        #pragma unroll
        for (int r = 0; r < 4; ++r) {
            int row = quad * 4 + r;
            int node = g * 16 + row;
            float v = fmaxf(acc[nt][r] + bj, 0.f);
            float vn = __shfl_xor(v, 1);          // neighbor feature (l15^1)
            if (((l15 & 1) == 0) && node < n) {
                unsigned pk = (unsigned)f2bf(v) | ((unsigned)f2bf(vn) << 16);
                hb[((size_t)node << 5) + ((nt * 16 + l15) >> 1)] = pk;
            }
        }
    }
}

// ---------------------------------------------------------------------------
// Gate from packed-bf16 hb: 2 edges per wave-gather; tanh(mean d^2) -> out.
// ---------------------------------------------------------------------------
__global__ __launch_bounds__(256) void gate_kernel(
    const unsigned* __restrict__ hb, const int* __restrict__ off_row,
    const int* __restrict__ by_row, float* __restrict__ out, int n)
{
    int lane = threadIdx.x & 63;
    int u = (blockIdx.x * blockDim.x + threadIdx.x) >> 6;
    if (u >= n) return;
    int half = lane >> 5, fl = lane & 31;
    int s0 = off_row[u], s1 = off_row[u + 1];
    unsigned hp = hb[((size_t)u << 5) + fl];
    float hu0 = bf2f((unsigned short)(hp & 0xFFFF));
    float hu1 = bf2f((unsigned short)(hp >> 16));
    float acc0 = 0.f, acc1 = 0.f;
    for (int base = s0; base < s1; base += 64) {
        int m = s1 - base;
        if (m > 64) m = 64;
        int idx = (lane < m) ? by_row[base + lane] : 0;
        for (int j = 0; j < m; j += 8) {
            unsigned vv[4];
            bool ok[4];
            #pragma unroll
            for (int p = 0; p < 4; ++p) {
                int jj = j + 2 * p + half;
                int e = __shfl(idx, jj & 63);
                ok[p] = jj < m;
                vv[p] = hb[((size_t)e << 5) + fl];
            }
            #pragma unroll
            for (int p = 0; p < 4; ++p) {
                if (ok[p]) {
                    float d0 = hu0 - bf2f((unsigned short)(vv[p] & 0xFFFF));
                    float d1 = hu1 - bf2f((unsigned short)(vv[p] >> 16));
                    acc0 += d0 * d0;
                    acc1 += d1 * d1;
                }
            }
        }
    }
    acc0 += __shfl_xor(acc0, 32);
    acc1 += __shfl_xor(acc1, 32);
    if (lane < 32) {
        float inv = 1.f / fmaxf((float)(s1 - s0), 1.f);
        float2 o;
        o.x = tanhf(acc0 * inv);
        o.y = tanhf(acc1 * inv);
        ((float2*)out)[((size_t)u << 5) + fl] = o;
    }
}

extern "C" void kernel_launch(void* const* d_in, const int* in_sizes, int n_in,
                              void* d_out, int out_size, void* d_ws, size_t ws_size,
                              hipStream_t stream) {
    const float* X  = (const float*)d_in[0];
    const int*   ei = (const int*)d_in[1];
    const float* Wl = (const float*)d_in[2];
    const float* Wr = (const float*)d_in[3];
    const float* b  = (const float*)d_in[4];
    float* out = (float*)d_out;

    int n = in_sizes[0] / D;
    int n_edges = in_sizes[1] / 2;
    int nbk = (n + 127) >> 7;
    int nchunks = (n_edges + CHUNK - 1) / CHUNK;

    // ws layout (~72 MB)
    float* agg = (float*)d_ws;                                       // n*64 f32
    unsigned* xb = (unsigned*)(agg + (size_t)n * D);                 // n*32 u32
    unsigned* hbuf = xb + (size_t)n * 32;                            // n*32 u32
    unsigned short* wpack = (unsigned short*)(hbuf + (size_t)n * 32);// 16384
    int* w = (int*)(wpack + 16384);
    int* bc_col    = w;                    // nbk
    int* bc_row    = bc_col + nbk;         // nbk
    int* bbase_col = bc_row + nbk;         // nbk
    int* bbase_row = bbase_col + nbk;      // nbk
    int* gcur_col  = bbase_row + nbk;      // nbk
    int* gcur_row  = gcur_col + nbk;       // nbk
    int* off_col   = gcur_row + nbk;       // n+1
    int* off_row   = off_col + (n + 1);    // n+1
    unsigned* ecol = (unsigned*)(off_row + (n + 1));   // n_edges
    unsigned* erow = ecol + n_edges;                   // n_edges
    int* by_col = (int*)(erow + n_edges);              // n_edges
    int* by_row = by_col + n_edges;                    // n_edges

    hipMemsetAsync(bc_col, 0, (size_t)2 * nbk * sizeof(int), stream);

    convert_x<<<((size_t)n * 32 + 255) / 256, 256, 0, stream>>>(X, xb, n * 32);
    bucket_hist<<<nchunks, MS_T, 0, stream>>>(ei, n_edges, nbk, bc_col, bc_row);
    bucket_scan<<<1, 64, 0, stream>>>(bc_col, bc_row, bbase_col, bbase_row,
                                      gcur_col, gcur_row, nbk);
    multisplit<<<nchunks, MS_T, 0, stream>>>(ei, n_edges, nbk,
                                             gcur_col, gcur_row, ecol, erow);
    csr_build<<<2 * nbk, 256, 0, stream>>>(ecol, erow, bbase_col, bbase_row,
                                           bc_col, bc_row, off_col, off_row,
                                           by_col, by_row, n, nbk);

    pack_w<<<1, 256, 0, stream>>>(Wl, Wr, wpack);

    agg_gather<<<(n + 3) / 4, 256, 0, stream>>>(xb, off_col, by_col, agg, n);

    int ngroups = (n + 15) / 16;
    linear_mfma<<<(ngroups + 3) / 4, 256, 0, stream>>>(X, agg, wpack, b, hbuf,
                                                       n, ngroups);

    gate_kernel<<<(n + 3) / 4, 256, 0, stream>>>(hbuf, off_row, by_row, out, n);
}

// Round 9
// 272.160 us; speedup vs baseline: 6.9218x; 1.0186x over previous
//
#include <hip/hip_runtime.h>
#include <math.h>

#define D 64
#define CHUNK 8192
#define MS_T 1024
#define EPT 8           // CHUNK / MS_T
#define MAXNB 800       // >= nbk = ceil(n/128); n=100000 -> 782

typedef __attribute__((ext_vector_type(8))) short frag_ab;
typedef __attribute__((ext_vector_type(4))) float frag_cd;

__device__ __forceinline__ unsigned short f2bf(float f) {
    unsigned u = __float_as_uint(f);
    u += 0x7FFFu + ((u >> 16) & 1u);
    return (unsigned short)(u >> 16);
}
__device__ __forceinline__ float bf2f(unsigned short s) {
    return __uint_as_float(((unsigned)s) << 16);
}

// ---------------------------------------------------------------------------
// X (fp32) -> packed bf16 pairs (halves gather bytes in agg_gather)
// ---------------------------------------------------------------------------
__global__ __launch_bounds__(256) void convert_x(
    const float* __restrict__ X, unsigned* __restrict__ xb, int total)
{
    int i = blockIdx.x * blockDim.x + threadIdx.x;
    if (i >= total) return;
    float2 v = ((const float2*)X)[i];
    xb[i] = (unsigned)f2bf(v.x) | ((unsigned)f2bf(v.y) << 16);
}

// ---------------------------------------------------------------------------
// Per-chunk LDS histogram over 128-node buckets
// ---------------------------------------------------------------------------
__global__ __launch_bounds__(MS_T) void bucket_hist(
    const int* __restrict__ ei, int n_edges, int nbk,
    int* __restrict__ bc_col, int* __restrict__ bc_row)
{
    __shared__ int scol[MAXNB];
    __shared__ int srow[MAXNB];
    for (int t = threadIdx.x; t < nbk; t += MS_T) {
        scol[t] = 0;
        srow[t] = 0;
    }
    __syncthreads();

    int base = blockIdx.x * CHUNK;
    int cc = n_edges - base;
    if (cc > CHUNK) cc = CHUNK;
    #pragma unroll
    for (int k = 0; k < EPT; ++k) {
        int i = threadIdx.x + k * MS_T;
        if (i < cc) {
            int r = ei[base + i];
            int c = ei[n_edges + base + i];
            atomicAdd(&srow[r >> 7], 1);
            atomicAdd(&scol[c >> 7], 1);
        }
    }
    __syncthreads();
    for (int t = threadIdx.x; t < nbk; t += MS_T) {
        if (scol[t]) atomicAdd(&bc_col[t], scol[t]);
        if (srow[t]) atomicAdd(&bc_row[t], srow[t]);
    }
}

// ---------------------------------------------------------------------------
// scan 782 bucket counts -> bases; init cursors (verified)
// ---------------------------------------------------------------------------
__global__ __launch_bounds__(64) void bucket_scan(
    const int* __restrict__ bc_col, const int* __restrict__ bc_row,
    int* __restrict__ bbase_col, int* __restrict__ bbase_row,
    int* __restrict__ gcur_col, int* __restrict__ gcur_row, int nbk)
{
    int lane = threadIdx.x;
    for (int w = 0; w < 2; ++w) {
        const int* bc = w ? bc_row : bc_col;
        int* bb = w ? bbase_row : bbase_col;
        int* gc = w ? gcur_row : gcur_col;
        int carry = 0;
        for (int b0 = 0; b0 < nbk; b0 += 64) {
            int v = (b0 + lane < nbk) ? bc[b0 + lane] : 0;
            int x = v;
            #pragma unroll
            for (int o = 1; o < 64; o <<= 1) {
                int u = __shfl_up(x, o);
                if (lane >= o) x += u;
            }
            if (b0 + lane < nbk) {
                int e = carry + x - v;
                bb[b0 + lane] = e;
                gc[b0 + lane] = e;
            }
            carry += __shfl(x, 63);
        }
    }
}

// ---------------------------------------------------------------------------
// Multisplit (verified R6 algorithm; CHUNK 8192 / 1024 threads: half the
// cursor atomics, 2x longer coalesced write runs)
// ---------------------------------------------------------------------------
__global__ __launch_bounds__(MS_T) void multisplit(
    const int* __restrict__ ei, int n_edges, int nbk,
    int* __restrict__ gcur_col, int* __restrict__ gcur_row,
    unsigned* __restrict__ ecol, unsigned* __restrict__ erow)
{
    __shared__ unsigned stage[CHUNK];
    __shared__ unsigned short sbk[CHUNK];
    __shared__ int cnt[MAXNB];
    __shared__ int off[MAXNB + 1];
    __shared__ int gb[MAXNB];

    int base = blockIdx.x * CHUNK;
    int cc = n_edges - base;
    if (cc > CHUNK) cc = CHUNK;

    int r[EPT], c[EPT];
    #pragma unroll
    for (int k = 0; k < EPT; ++k) {
        int i = threadIdx.x + k * MS_T;
        if (i < cc) {
            r[k] = ei[base + i];
            c[k] = ei[n_edges + base + i];
        }
    }

    for (int ord = 0; ord < 2; ++ord) {
        int* gcur = ord ? gcur_row : gcur_col;
        unsigned* eout = ord ? erow : ecol;

        for (int t = threadIdx.x; t < nbk; t += MS_T) cnt[t] = 0;
        __syncthreads();

        int rk[EPT], bk[EPT];
        #pragma unroll
        for (int k = 0; k < EPT; ++k) {
            int i = threadIdx.x + k * MS_T;
            if (i < cc) {
                int key = ord ? r[k] : c[k];
                bk[k] = key >> 7;
                rk[k] = atomicAdd(&cnt[bk[k]], 1);
            }
        }
        __syncthreads();

        if (threadIdx.x < 64) {           // wave 0: scan + global reservation
            int lane = threadIdx.x;
            int carry = 0;
            for (int b0 = 0; b0 < nbk; b0 += 64) {
                int v = (b0 + lane < nbk) ? cnt[b0 + lane] : 0;
                int x = v;
                #pragma unroll
                for (int o = 1; o < 64; o <<= 1) {
                    int u = __shfl_up(x, o);
                    if (lane >= o) x += u;
                }
                if (b0 + lane < nbk) {
                    off[b0 + lane] = carry + x - v;
                    gb[b0 + lane] = v ? atomicAdd(&gcur[b0 + lane], v) : 0;
                }
                carry += __shfl(x, 63);
            }
        }
        __syncthreads();

        #pragma unroll
        for (int k = 0; k < EPT; ++k) {
            int i = threadIdx.x + k * MS_T;
            if (i < cc) {
                int key = ord ? r[k] : c[k];
                int oth = ord ? c[k] : r[k];
                int p = off[bk[k]] + rk[k];
                stage[p] = ((unsigned)(key & 127) << 17) | (unsigned)oth;
                sbk[p] = (unsigned short)bk[k];
            }
        }
        __syncthreads();

        for (int t = threadIdx.x; t < cc; t += MS_T) {
            int bb = sbk[t];
            eout[gb[bb] + (t - off[bb])] = stage[t];
        }
        __syncthreads();
    }
}

// ---------------------------------------------------------------------------
// csr_build (R7-verified): bucket entries -> exact per-node CSR.
// ---------------------------------------------------------------------------
__global__ __launch_bounds__(256) void csr_build(
    const unsigned* __restrict__ ecol, const unsigned* __restrict__ erow,
    const int* __restrict__ bbase_col, const int* __restrict__ bbase_row,
    const int* __restrict__ bc_col, const int* __restrict__ bc_row,
    int* __restrict__ off_col, int* __restrict__ off_row,
    int* __restrict__ by_col, int* __restrict__ by_row, int n, int nbk)
{
    __shared__ int scnt[128];
    __shared__ int soff[129];
    bool isRow = blockIdx.x >= (unsigned)nbk;
    int b = isRow ? (blockIdx.x - nbk) : blockIdx.x;
    const unsigned* e = isRow ? erow : ecol;
    int base = (isRow ? bbase_row : bbase_col)[b];
    int ec = (isRow ? bc_row : bc_col)[b];
    int* off_g = isRow ? off_row : off_col;
    int* by = isRow ? by_row : by_col;

    int node0 = b << 7;
    int nn = n - node0;
    if (nn > 128) nn = 128;

    if (threadIdx.x < 128) scnt[threadIdx.x] = 0;
    __syncthreads();

    for (int t = threadIdx.x; t < ec; t += 256)
        atomicAdd(&scnt[e[base + t] >> 17], 1);
    __syncthreads();

    if (threadIdx.x < 64) {
        int lane = threadIdx.x;
        int carry = 0;
        #pragma unroll
        for (int b0 = 0; b0 < 128; b0 += 64) {
            int v = scnt[b0 + lane];
            int x = v;
            #pragma unroll
            for (int o = 1; o < 64; o <<= 1) {
                int u = __shfl_up(x, o);
                if (lane >= o) x += u;
            }
            soff[b0 + lane] = carry + x - v;
            carry += __shfl(x, 63);
        }
        if (lane == 63) soff[128] = carry;
    }
    __syncthreads();

    if (threadIdx.x < 128) {
        if (threadIdx.x < nn) off_g[node0 + threadIdx.x] = base + soff[threadIdx.x];
        scnt[threadIdx.x] = 0;
    }
    if (threadIdx.x == 0 && node0 + nn == n) off_g[n] = base + soff[nn];
    __syncthreads();

    for (int t = threadIdx.x; t < ec; t += 256) {
        unsigned ent = e[base + t];
        int slot = ent >> 17;
        int r = atomicAdd(&scnt[slot], 1);
        by[base + soff[slot] + r] = (int)(ent & 0x1FFFF);
    }
}

// ---------------------------------------------------------------------------
// CSR mean-aggregate: 16 lanes/edge, uint2 loads -> 4 edges per wave-instr,
// p-unroll 2 (2 loads in flight/lane). fp32 accumulate, float4 store.
// ---------------------------------------------------------------------------
__global__ __launch_bounds__(256) void agg_gather(
    const unsigned* __restrict__ xb, const int* __restrict__ off_col,
    const int* __restrict__ by_col, float* __restrict__ agg, int n)
{
    int lane = threadIdx.x & 63;
    int node = (blockIdx.x * blockDim.x + threadIdx.x) >> 6;
    if (node >= n) return;
    int fl = lane & 15, q = lane >> 4;
    int s0 = off_col[node], s1 = off_col[node + 1];
    float a0 = 0.f, a1 = 0.f, a2 = 0.f, a3 = 0.f;
    for (int base = s0; base < s1; base += 64) {
        int m = s1 - base;
        if (m > 64) m = 64;
        int idx = (lane < m) ? by_col[base + lane] : 0;
        for (int j = 0; j < m; j += 8) {
            #pragma unroll
            for (int p = 0; p < 2; ++p) {
                int jj = j + 4 * p + q;
                int e = __shfl(idx, jj);          // idx=0 when masked: safe addr
                uint2 v = ((const uint2*)xb)[((size_t)e << 4) + fl];
                if (jj < m) {
                    a0 += bf2f((unsigned short)(v.x & 0xFFFF));
                    a1 += bf2f((unsigned short)(v.x >> 16));
                    a2 += bf2f((unsigned short)(v.y & 0xFFFF));
                    a3 += bf2f((unsigned short)(v.y >> 16));
                }
            }
        }
    }
    a0 += __shfl_xor(a0, 16); a0 += __shfl_xor(a0, 32);
    a1 += __shfl_xor(a1, 16); a1 += __shfl_xor(a1, 32);
    a2 += __shfl_xor(a2, 16); a2 += __shfl_xor(a2, 32);
    a3 += __shfl_xor(a3, 16); a3 += __shfl_xor(a3, 32);
    if (lane < 16) {
        float inv = 1.f / fmaxf((float)(s1 - s0), 1.f);
        float4 o;
        o.x = a0 * inv; o.y = a1 * inv; o.z = a2 * inv; o.w = a3 * inv;
        ((float4*)agg)[((size_t)node << 4) + fl] = o;
    }
}

// ---------------------------------------------------------------------------
// pack_w (R4-verified)
// ---------------------------------------------------------------------------
__global__ __launch_bounds__(256) void pack_w(
    const float* __restrict__ Wl, const float* __restrict__ Wr,
    unsigned short* __restrict__ wpack)
{
    for (int c = threadIdx.x; c < 8192; c += 256) {
        int j = c & 7;
        int lane = (c >> 3) & 63;
        int tile = (c >> 9) & 7;
        int mat = c >> 12;
        int kc = tile >> 2;
        int nt = tile & 3;
        int krow = (lane >> 4) * 8 + j + kc * 32;
        int col = (lane & 15) + nt * 16;
        const float* W = mat ? Wr : Wl;
        float v = W[krow * 64 + col];
        unsigned short hi = f2bf(v);
        unsigned short lo = f2bf(v - bf2f(hi));
        int base = mat * 8192 + tile * 512 + lane * 8 + j;
        wpack[base] = hi;
        wpack[base + 4096] = lo;
    }
}

// ---------------------------------------------------------------------------
// linear_mfma (R4-verified math); epilogue writes packed-bf16 hb only.
// ---------------------------------------------------------------------------
__global__ __launch_bounds__(256) void linear_mfma(
    const float* __restrict__ X, const float* __restrict__ agg,
    const unsigned short* __restrict__ wpack, const float* __restrict__ b,
    unsigned* __restrict__ hb, int n, int ngroups)
{
    int lane = threadIdx.x & 63;
    int g = (blockIdx.x * blockDim.x + threadIdx.x) >> 6;
    if (g >= ngroups) return;
    int quad = lane >> 4;
    int l15 = lane & 15;

    frag_ab wf[2][2][2][4];
    #pragma unroll
    for (int mat = 0; mat < 2; ++mat)
        #pragma unroll
        for (int hf = 0; hf < 2; ++hf)
            #pragma unroll
            for (int kc = 0; kc < 2; ++kc)
                #pragma unroll
                for (int nt = 0; nt < 4; ++nt) {
                    const unsigned short* p =
                        wpack + mat * 8192 + hf * 4096 + (kc * 4 + nt) * 512 + lane * 8;
                    wf[mat][hf][kc][nt] = *(const frag_ab*)p;
                }

    frag_cd acc[4];
    #pragma unroll
    for (int nt = 0; nt < 4; ++nt) acc[nt] = (frag_cd){0.f, 0.f, 0.f, 0.f};

    int mrow = g * 16 + l15;
    if (mrow >= n) mrow = n - 1;
    const float* arow = agg + ((size_t)mrow << 6) + quad * 8;
    const float* xrow = X + ((size_t)mrow << 6) + quad * 8;

    #pragma unroll
    for (int kc = 0; kc < 2; ++kc) {
        float av[8], xv[8];
        #pragma unroll
        for (int t = 0; t < 2; ++t) {
            float4 a4 = *(const float4*)(arow + kc * 32 + t * 4);
            float4 x4 = *(const float4*)(xrow + kc * 32 + t * 4);
            av[t * 4 + 0] = a4.x; av[t * 4 + 1] = a4.y;
            av[t * 4 + 2] = a4.z; av[t * 4 + 3] = a4.w;
            xv[t * 4 + 0] = x4.x; xv[t * 4 + 1] = x4.y;
            xv[t * 4 + 2] = x4.z; xv[t * 4 + 3] = x4.w;
        }
        frag_ab ah, al, xh, xl;
        #pragma unroll
        for (int j = 0; j < 8; ++j) {
            unsigned short hbv = f2bf(av[j]);
            ah[j] = (short)hbv;
            al[j] = (short)f2bf(av[j] - bf2f(hbv));
            unsigned short xbv = f2bf(xv[j]);
            xh[j] = (short)xbv;
            xl[j] = (short)f2bf(xv[j] - bf2f(xbv));
        }
        #pragma unroll
        for (int nt = 0; nt < 4; ++nt) {
            acc[nt] = __builtin_amdgcn_mfma_f32_16x16x32_bf16(ah, wf[0][0][kc][nt], acc[nt], 0, 0, 0);
            acc[nt] = __builtin_amdgcn_mfma_f32_16x16x32_bf16(ah, wf[0][1][kc][nt], acc[nt], 0, 0, 0);
            acc[nt] = __builtin_amdgcn_mfma_f32_16x16x32_bf16(al, wf[0][0][kc][nt], acc[nt], 0, 0, 0);
            acc[nt] = __builtin_amdgcn_mfma_f32_16x16x32_bf16(xh, wf[1][0][kc][nt], acc[nt], 0, 0, 0);
            acc[nt] = __builtin_amdgcn_mfma_f32_16x16x32_bf16(xh, wf[1][1][kc][nt], acc[nt], 0, 0, 0);
            acc[nt] = __builtin_amdgcn_mfma_f32_16x16x32_bf16(xl, wf[1][0][kc][nt], acc[nt], 0, 0, 0);
        }
    }

    #pragma unroll
    for (int nt = 0; nt < 4; ++nt) {
        float bj = b[l15 + nt * 16];
        #pragma unroll
        for (int r = 0; r < 4; ++r) {
            int row = quad * 4 + r;
            int node = g * 16 + row;
            float v = fmaxf(acc[nt][r] + bj, 0.f);
            float vn = __shfl_xor(v, 1);          // neighbor feature (l15^1)
            if (((l15 & 1) == 0) && node < n) {
                unsigned pk = (unsigned)f2bf(v) | ((unsigned)f2bf(vn) << 16);
                hb[((size_t)node << 5) + ((nt * 16 + l15) >> 1)] = pk;
            }
        }
    }
}

// ---------------------------------------------------------------------------
// Gate: 16 lanes/edge, uint2 loads -> 4 edges per wave-instr, p-unroll 2.
// tanh(mean d^2) per feature; float4 store.
// ---------------------------------------------------------------------------
__global__ __launch_bounds__(256) void gate_kernel(
    const unsigned* __restrict__ hb, const int* __restrict__ off_row,
    const int* __restrict__ by_row, float* __restrict__ out, int n)
{
    int lane = threadIdx.x & 63;
    int u = (blockIdx.x * blockDim.x + threadIdx.x) >> 6;
    if (u >= n) return;
    int fl = lane & 15, q = lane >> 4;
    int s0 = off_row[u], s1 = off_row[u + 1];
    uint2 hp = ((const uint2*)hb)[((size_t)u << 4) + fl];
    float f0 = bf2f((unsigned short)(hp.x & 0xFFFF));
    float f1 = bf2f((unsigned short)(hp.x >> 16));
    float f2 = bf2f((unsigned short)(hp.y & 0xFFFF));
    float f3 = bf2f((unsigned short)(hp.y >> 16));
    float a0 = 0.f, a1 = 0.f, a2 = 0.f, a3 = 0.f;
    for (int base = s0; base < s1; base += 64) {
        int m = s1 - base;
        if (m > 64) m = 64;
        int idx = (lane < m) ? by_row[base + lane] : 0;
        for (int j = 0; j < m; j += 8) {
            #pragma unroll
            for (int p = 0; p < 2; ++p) {
                int jj = j + 4 * p + q;
                int e = __shfl(idx, jj);
                uint2 v = ((const uint2*)hb)[((size_t)e << 4) + fl];
                if (jj < m) {
                    float d0 = f0 - bf2f((unsigned short)(v.x & 0xFFFF));
                    float d1 = f1 - bf2f((unsigned short)(v.x >> 16));
                    float d2 = f2 - bf2f((unsigned short)(v.y & 0xFFFF));
                    float d3 = f3 - bf2f((unsigned short)(v.y >> 16));
                    a0 += d0 * d0; a1 += d1 * d1;
                    a2 += d2 * d2; a3 += d3 * d3;
                }
            }
        }
    }
    a0 += __shfl_xor(a0, 16); a0 += __shfl_xor(a0, 32);
    a1 += __shfl_xor(a1, 16); a1 += __shfl_xor(a1, 32);
    a2 += __shfl_xor(a2, 16); a2 += __shfl_xor(a2, 32);
    a3 += __shfl_xor(a3, 16); a3 += __shfl_xor(a3, 32);
    if (lane < 16) {
        float inv = 1.f / fmaxf((float)(s1 - s0), 1.f);
        float4 o;
        o.x = tanhf(a0 * inv);
        o.y = tanhf(a1 * inv);
        o.z = tanhf(a2 * inv);
        o.w = tanhf(a3 * inv);
        ((float4*)out)[((size_t)u << 4) + fl] = o;
    }
}

extern "C" void kernel_launch(void* const* d_in, const int* in_sizes, int n_in,
                              void* d_out, int out_size, void* d_ws, size_t ws_size,
                              hipStream_t stream) {
    const float* X  = (const float*)d_in[0];
    const int*   ei = (const int*)d_in[1];
    const float* Wl = (const float*)d_in[2];
    const float* Wr = (const float*)d_in[3];
    const float* b  = (const float*)d_in[4];
    float* out = (float*)d_out;

    int n = in_sizes[0] / D;
    int n_edges = in_sizes[1] / 2;
    int nbk = (n + 127) >> 7;
    int nchunks = (n_edges + CHUNK - 1) / CHUNK;

    // ws layout (~72 MB)
    float* agg = (float*)d_ws;                                       // n*64 f32
    unsigned* xb = (unsigned*)(agg + (size_t)n * D);                 // n*32 u32
    unsigned* hbuf = xb + (size_t)n * 32;                            // n*32 u32
    unsigned short* wpack = (unsigned short*)(hbuf + (size_t)n * 32);// 16384
    int* w = (int*)(wpack + 16384);
    int* bc_col    = w;                    // nbk
    int* bc_row    = bc_col + nbk;         // nbk
    int* bbase_col = bc_row + nbk;         // nbk
    int* bbase_row = bbase_col + nbk;      // nbk
    int* gcur_col  = bbase_row + nbk;      // nbk
    int* gcur_row  = gcur_col + nbk;       // nbk
    int* off_col   = gcur_row + nbk;       // n+1
    int* off_row   = off_col + (n + 1);    // n+1
    unsigned* ecol = (unsigned*)(off_row + (n + 1));   // n_edges
    unsigned* erow = ecol + n_edges;                   // n_edges
    int* by_col = (int*)(erow + n_edges);              // n_edges
    int* by_row = by_col + n_edges;                    // n_edges

    hipMemsetAsync(bc_col, 0, (size_t)2 * nbk * sizeof(int), stream);

    convert_x<<<((size_t)n * 32 + 255) / 256, 256, 0, stream>>>(X, xb, n * 32);
    bucket_hist<<<nchunks, MS_T, 0, stream>>>(ei, n_edges, nbk, bc_col, bc_row);
    bucket_scan<<<1, 64, 0, stream>>>(bc_col, bc_row, bbase_col, bbase_row,
                                      gcur_col, gcur_row, nbk);
    multisplit<<<nchunks, MS_T, 0, stream>>>(ei, n_edges, nbk,
                                             gcur_col, gcur_row, ecol, erow);
    csr_build<<<2 * nbk, 256, 0, stream>>>(ecol, erow, bbase_col, bbase_row,
                                           bc_col, bc_row, off_col, off_row,
                                           by_col, by_row, n, nbk);

    pack_w<<<1, 256, 0, stream>>>(Wl, Wr, wpack);

    agg_gather<<<(n + 3) / 4, 256, 0, stream>>>(xb, off_col, by_col, agg, n);

    int ngroups = (n + 15) / 16;
    linear_mfma<<<(ngroups + 3) / 4, 256, 0, stream>>>(X, agg, wpack, b, hbuf,
                                                       n, ngroups);

    gate_kernel<<<(n + 3) / 4, 256, 0, stream>>>(hbuf, off_row, by_row, out, n);
}

// Round 10
// 257.186 us; speedup vs baseline: 7.3248x; 1.0582x over previous
//
#include <hip/hip_runtime.h>
#include <math.h>

#define D 64
#define CHUNK 8192
#define MS_T 1024
#define EPT 8           // CHUNK / MS_T
#define MAXNB 800       // >= nbk = ceil(n/128); n=100000 -> 782

typedef __attribute__((ext_vector_type(8))) short frag_ab;
typedef __attribute__((ext_vector_type(4))) float frag_cd;

__device__ __forceinline__ unsigned short f2bf(float f) {
    unsigned u = __float_as_uint(f);
    u += 0x7FFFu + ((u >> 16) & 1u);
    return (unsigned short)(u >> 16);
}
__device__ __forceinline__ float bf2f(unsigned short s) {
    return __uint_as_float(((unsigned)s) << 16);
}

// ---------------------------------------------------------------------------
// X (fp32) -> packed bf16 pairs; row n (index total..total2) = zeros, used
// as the branch-free masked-lane target in agg_gather.
// ---------------------------------------------------------------------------
__global__ __launch_bounds__(256) void convert_x(
    const float* __restrict__ X, unsigned* __restrict__ xb, int total,
    int total2)
{
    int i = blockIdx.x * blockDim.x + threadIdx.x;
    if (i >= total2) return;
    if (i < total) {
        float2 v = ((const float2*)X)[i];
        xb[i] = (unsigned)f2bf(v.x) | ((unsigned)f2bf(v.y) << 16);
    } else {
        xb[i] = 0u;
    }
}

// ---------------------------------------------------------------------------
// Per-chunk LDS histogram over 128-node buckets (verified)
// ---------------------------------------------------------------------------
__global__ __launch_bounds__(MS_T) void bucket_hist(
    const int* __restrict__ ei, int n_edges, int nbk,
    int* __restrict__ bc_col, int* __restrict__ bc_row)
{
    __shared__ int scol[MAXNB];
    __shared__ int srow[MAXNB];
    for (int t = threadIdx.x; t < nbk; t += MS_T) {
        scol[t] = 0;
        srow[t] = 0;
    }
    __syncthreads();

    int base = blockIdx.x * CHUNK;
    int cc = n_edges - base;
    if (cc > CHUNK) cc = CHUNK;
    #pragma unroll
    for (int k = 0; k < EPT; ++k) {
        int i = threadIdx.x + k * MS_T;
        if (i < cc) {
            int r = ei[base + i];
            int c = ei[n_edges + base + i];
            atomicAdd(&srow[r >> 7], 1);
            atomicAdd(&scol[c >> 7], 1);
        }
    }
    __syncthreads();
    for (int t = threadIdx.x; t < nbk; t += MS_T) {
        if (scol[t]) atomicAdd(&bc_col[t], scol[t]);
        if (srow[t]) atomicAdd(&bc_row[t], srow[t]);
    }
}

// ---------------------------------------------------------------------------
// scan 782 bucket counts -> bases; init cursors (verified)
// ---------------------------------------------------------------------------
__global__ __launch_bounds__(64) void bucket_scan(
    const int* __restrict__ bc_col, const int* __restrict__ bc_row,
    int* __restrict__ bbase_col, int* __restrict__ bbase_row,
    int* __restrict__ gcur_col, int* __restrict__ gcur_row, int nbk)
{
    int lane = threadIdx.x;
    for (int w = 0; w < 2; ++w) {
        const int* bc = w ? bc_row : bc_col;
        int* bb = w ? bbase_row : bbase_col;
        int* gc = w ? gcur_row : gcur_col;
        int carry = 0;
        for (int b0 = 0; b0 < nbk; b0 += 64) {
            int v = (b0 + lane < nbk) ? bc[b0 + lane] : 0;
            int x = v;
            #pragma unroll
            for (int o = 1; o < 64; o <<= 1) {
                int u = __shfl_up(x, o);
                if (lane >= o) x += u;
            }
            if (b0 + lane < nbk) {
                int e = carry + x - v;
                bb[b0 + lane] = e;
                gc[b0 + lane] = e;
            }
            carry += __shfl(x, 63);
        }
    }
}

// ---------------------------------------------------------------------------
// Multisplit (verified): group edges into 128-node buckets, both orders.
// ---------------------------------------------------------------------------
__global__ __launch_bounds__(MS_T) void multisplit(
    const int* __restrict__ ei, int n_edges, int nbk,
    int* __restrict__ gcur_col, int* __restrict__ gcur_row,
    unsigned* __restrict__ ecol, unsigned* __restrict__ erow)
{
    __shared__ unsigned stage[CHUNK];
    __shared__ unsigned short sbk[CHUNK];
    __shared__ int cnt[MAXNB];
    __shared__ int off[MAXNB + 1];
    __shared__ int gb[MAXNB];

    int base = blockIdx.x * CHUNK;
    int cc = n_edges - base;
    if (cc > CHUNK) cc = CHUNK;

    int r[EPT], c[EPT];
    #pragma unroll
    for (int k = 0; k < EPT; ++k) {
        int i = threadIdx.x + k * MS_T;
        if (i < cc) {
            r[k] = ei[base + i];
            c[k] = ei[n_edges + base + i];
        }
    }

    for (int ord = 0; ord < 2; ++ord) {
        int* gcur = ord ? gcur_row : gcur_col;
        unsigned* eout = ord ? erow : ecol;

        for (int t = threadIdx.x; t < nbk; t += MS_T) cnt[t] = 0;
        __syncthreads();

        int rk[EPT], bk[EPT];
        #pragma unroll
        for (int k = 0; k < EPT; ++k) {
            int i = threadIdx.x + k * MS_T;
            if (i < cc) {
                int key = ord ? r[k] : c[k];
                bk[k] = key >> 7;
                rk[k] = atomicAdd(&cnt[bk[k]], 1);
            }
        }
        __syncthreads();

        if (threadIdx.x < 64) {           // wave 0: scan + global reservation
            int lane = threadIdx.x;
            int carry = 0;
            for (int b0 = 0; b0 < nbk; b0 += 64) {
                int v = (b0 + lane < nbk) ? cnt[b0 + lane] : 0;
                int x = v;
                #pragma unroll
                for (int o = 1; o < 64; o <<= 1) {
                    int u = __shfl_up(x, o);
                    if (lane >= o) x += u;
                }
                if (b0 + lane < nbk) {
                    off[b0 + lane] = carry + x - v;
                    gb[b0 + lane] = v ? atomicAdd(&gcur[b0 + lane], v) : 0;
                }
                carry += __shfl(x, 63);
            }
        }
        __syncthreads();

        #pragma unroll
        for (int k = 0; k < EPT; ++k) {
            int i = threadIdx.x + k * MS_T;
            if (i < cc) {
                int key = ord ? r[k] : c[k];
                int oth = ord ? c[k] : r[k];
                int p = off[bk[k]] + rk[k];
                stage[p] = ((unsigned)(key & 127) << 17) | (unsigned)oth;
                sbk[p] = (unsigned short)bk[k];
            }
        }
        __syncthreads();

        for (int t = threadIdx.x; t < cc; t += MS_T) {
            int bb = sbk[t];
            eout[gb[bb] + (t - off[bb])] = stage[t];
        }
        __syncthreads();
    }
}

// ---------------------------------------------------------------------------
// csr_build (verified): bucket entries -> exact per-node CSR.
// ---------------------------------------------------------------------------
__global__ __launch_bounds__(256) void csr_build(
    const unsigned* __restrict__ ecol, const unsigned* __restrict__ erow,
    const int* __restrict__ bbase_col, const int* __restrict__ bbase_row,
    const int* __restrict__ bc_col, const int* __restrict__ bc_row,
    int* __restrict__ off_col, int* __restrict__ off_row,
    int* __restrict__ by_col, int* __restrict__ by_row, int n, int nbk)
{
    __shared__ int scnt[128];
    __shared__ int soff[129];
    bool isRow = blockIdx.x >= (unsigned)nbk;
    int b = isRow ? (blockIdx.x - nbk) : blockIdx.x;
    const unsigned* e = isRow ? erow : ecol;
    int base = (isRow ? bbase_row : bbase_col)[b];
    int ec = (isRow ? bc_row : bc_col)[b];
    int* off_g = isRow ? off_row : off_col;
    int* by = isRow ? by_row : by_col;

    int node0 = b << 7;
    int nn = n - node0;
    if (nn > 128) nn = 128;

    if (threadIdx.x < 128) scnt[threadIdx.x] = 0;
    __syncthreads();

    for (int t = threadIdx.x; t < ec; t += 256)
        atomicAdd(&scnt[e[base + t] >> 17], 1);
    __syncthreads();

    if (threadIdx.x < 64) {
        int lane = threadIdx.x;
        int carry = 0;
        #pragma unroll
        for (int b0 = 0; b0 < 128; b0 += 64) {
            int v = scnt[b0 + lane];
            int x = v;
            #pragma unroll
            for (int o = 1; o < 64; o <<= 1) {
                int u = __shfl_up(x, o);
                if (lane >= o) x += u;
            }
            soff[b0 + lane] = carry + x - v;
            carry += __shfl(x, 63);
        }
        if (lane == 63) soff[128] = carry;
    }
    __syncthreads();

    if (threadIdx.x < 128) {
        if (threadIdx.x < nn) off_g[node0 + threadIdx.x] = base + soff[threadIdx.x];
        scnt[threadIdx.x] = 0;
    }
    if (threadIdx.x == 0 && node0 + nn == n) off_g[n] = base + soff[nn];
    __syncthreads();

    for (int t = threadIdx.x; t < ec; t += 256) {
        unsigned ent = e[base + t];
        int slot = ent >> 17;
        int r = atomicAdd(&scnt[slot], 1);
        by[base + soff[slot] + r] = (int)(ent & 0x1FFFF);
    }
}

// ---------------------------------------------------------------------------
// CSR mean-aggregate: 16 lanes/edge, uint2 loads, p-unroll 4 (4 loads in
// flight), branch-free (masked slots -> zero row n). 1-op bf16 unpack.
// ---------------------------------------------------------------------------
__global__ __launch_bounds__(256) void agg_gather(
    const unsigned* __restrict__ xb, const int* __restrict__ off_col,
    const int* __restrict__ by_col, float* __restrict__ agg, int n)
{
    int lane = threadIdx.x & 63;
    int node = (blockIdx.x * blockDim.x + threadIdx.x) >> 6;
    if (node >= n) return;
    int fl = lane & 15, q = lane >> 4;
    int s0 = off_col[node], s1 = off_col[node + 1];
    float a0 = 0.f, a1 = 0.f, a2 = 0.f, a3 = 0.f;
    for (int base = s0; base < s1; base += 64) {
        int m = s1 - base;
        if (m > 64) m = 64;
        int idx = (lane < m) ? by_col[base + lane] : n;   // row n = zeros
        for (int j = 0; j < m; j += 16) {
            #pragma unroll
            for (int p = 0; p < 4; ++p) {
                int jj = j + 4 * p + q;                   // <= 63 always
                int e = __shfl(idx, jj);
                uint2 v = ((const uint2*)xb)[((size_t)e << 4) + fl];
                a0 += __uint_as_float(v.x << 16);
                a1 += __uint_as_float(v.x & 0xFFFF0000u);
                a2 += __uint_as_float(v.y << 16);
                a3 += __uint_as_float(v.y & 0xFFFF0000u);
            }
        }
    }
    a0 += __shfl_xor(a0, 16); a0 += __shfl_xor(a0, 32);
    a1 += __shfl_xor(a1, 16); a1 += __shfl_xor(a1, 32);
    a2 += __shfl_xor(a2, 16); a2 += __shfl_xor(a2, 32);
    a3 += __shfl_xor(a3, 16); a3 += __shfl_xor(a3, 32);
    if (lane < 16) {
        float inv = 1.f / fmaxf((float)(s1 - s0), 1.f);
        float4 o;
        o.x = a0 * inv; o.y = a1 * inv; o.z = a2 * inv; o.w = a3 * inv;
        ((float4*)agg)[((size_t)node << 4) + fl] = o;
    }
}

// ---------------------------------------------------------------------------
// pack_w (verified)
// ---------------------------------------------------------------------------
__global__ __launch_bounds__(256) void pack_w(
    const float* __restrict__ Wl, const float* __restrict__ Wr,
    unsigned short* __restrict__ wpack)
{
    for (int c = threadIdx.x; c < 8192; c += 256) {
        int j = c & 7;
        int lane = (c >> 3) & 63;
        int tile = (c >> 9) & 7;
        int mat = c >> 12;
        int kc = tile >> 2;
        int nt = tile & 3;
        int krow = (lane >> 4) * 8 + j + kc * 32;
        int col = (lane & 15) + nt * 16;
        const float* W = mat ? Wr : Wl;
        float v = W[krow * 64 + col];
        unsigned short hi = f2bf(v);
        unsigned short lo = f2bf(v - bf2f(hi));
        int base = mat * 8192 + tile * 512 + lane * 8 + j;
        wpack[base] = hi;
        wpack[base + 4096] = lo;
    }
}

// ---------------------------------------------------------------------------
// linear_mfma (verified math); epilogue writes packed-bf16 hb only.
// ---------------------------------------------------------------------------
__global__ __launch_bounds__(256) void linear_mfma(
    const float* __restrict__ X, const float* __restrict__ agg,
    const unsigned short* __restrict__ wpack, const float* __restrict__ b,
    unsigned* __restrict__ hb, int n, int ngroups)
{
    int lane = threadIdx.x & 63;
    int g = (blockIdx.x * blockDim.x + threadIdx.x) >> 6;
    if (g >= ngroups) return;
    int quad = lane >> 4;
    int l15 = lane & 15;

    frag_ab wf[2][2][2][4];
    #pragma unroll
    for (int mat = 0; mat < 2; ++mat)
        #pragma unroll
        for (int hf = 0; hf < 2; ++hf)
            #pragma unroll
            for (int kc = 0; kc < 2; ++kc)
                #pragma unroll
                for (int nt = 0; nt < 4; ++nt) {
                    const unsigned short* p =
                        wpack + mat * 8192 + hf * 4096 + (kc * 4 + nt) * 512 + lane * 8;
                    wf[mat][hf][kc][nt] = *(const frag_ab*)p;
                }

    frag_cd acc[4];
    #pragma unroll
    for (int nt = 0; nt < 4; ++nt) acc[nt] = (frag_cd){0.f, 0.f, 0.f, 0.f};

    int mrow = g * 16 + l15;
    if (mrow >= n) mrow = n - 1;
    const float* arow = agg + ((size_t)mrow << 6) + quad * 8;
    const float* xrow = X + ((size_t)mrow << 6) + quad * 8;

    #pragma unroll
    for (int kc = 0; kc < 2; ++kc) {
        float av[8], xv[8];
        #pragma unroll
        for (int t = 0; t < 2; ++t) {
            float4 a4 = *(const float4*)(arow + kc * 32 + t * 4);
            float4 x4 = *(const float4*)(xrow + kc * 32 + t * 4);
            av[t * 4 + 0] = a4.x; av[t * 4 + 1] = a4.y;
            av[t * 4 + 2] = a4.z; av[t * 4 + 3] = a4.w;
            xv[t * 4 + 0] = x4.x; xv[t * 4 + 1] = x4.y;
            xv[t * 4 + 2] = x4.z; xv[t * 4 + 3] = x4.w;
        }
        frag_ab ah, al, xh, xl;
        #pragma unroll
        for (int j = 0; j < 8; ++j) {
            unsigned short hbv = f2bf(av[j]);
            ah[j] = (short)hbv;
            al[j] = (short)f2bf(av[j] - bf2f(hbv));
            unsigned short xbv = f2bf(xv[j]);
            xh[j] = (short)xbv;
            xl[j] = (short)f2bf(xv[j] - bf2f(xbv));
        }
        #pragma unroll
        for (int nt = 0; nt < 4; ++nt) {
            acc[nt] = __builtin_amdgcn_mfma_f32_16x16x32_bf16(ah, wf[0][0][kc][nt], acc[nt], 0, 0, 0);
            acc[nt] = __builtin_amdgcn_mfma_f32_16x16x32_bf16(ah, wf[0][1][kc][nt], acc[nt], 0, 0, 0);
            acc[nt] = __builtin_amdgcn_mfma_f32_16x16x32_bf16(al, wf[0][0][kc][nt], acc[nt], 0, 0, 0);
            acc[nt] = __builtin_amdgcn_mfma_f32_16x16x32_bf16(xh, wf[1][0][kc][nt], acc[nt], 0, 0, 0);
            acc[nt] = __builtin_amdgcn_mfma_f32_16x16x32_bf16(xh, wf[1][1][kc][nt], acc[nt], 0, 0, 0);
            acc[nt] = __builtin_amdgcn_mfma_f32_16x16x32_bf16(xl, wf[1][0][kc][nt], acc[nt], 0, 0, 0);
        }
    }

    #pragma unroll
    for (int nt = 0; nt < 4; ++nt) {
        float bj = b[l15 + nt * 16];
        #pragma unroll
        for (int r = 0; r < 4; ++r) {
            int row = quad * 4 + r;
            int node = g * 16 + row;
            float v = fmaxf(acc[nt][r] + bj, 0.f);
            float vn = __shfl_xor(v, 1);          // neighbor feature (l15^1)
            if (((l15 & 1) == 0) && node < n) {
                unsigned pk = (unsigned)f2bf(v) | ((unsigned)f2bf(vn) << 16);
                hb[((size_t)node << 5) + ((nt * 16 + l15) >> 1)] = pk;
            }
        }
    }
}

// ---------------------------------------------------------------------------
// Gate: 16 lanes/edge, uint2 loads, p-unroll 4, branch-free (masked -> self,
// giving exact d=0). 1-op bf16 unpack. tanh(mean d^2); float4 store.
// ---------------------------------------------------------------------------
__global__ __launch_bounds__(256) void gate_kernel(
    const unsigned* __restrict__ hb, const int* __restrict__ off_row,
    const int* __restrict__ by_row, float* __restrict__ out, int n)
{
    int lane = threadIdx.x & 63;
    int u = (blockIdx.x * blockDim.x + threadIdx.x) >> 6;
    if (u >= n) return;
    int fl = lane & 15, q = lane >> 4;
    int s0 = off_row[u], s1 = off_row[u + 1];
    uint2 hp = ((const uint2*)hb)[((size_t)u << 4) + fl];
    float f0 = __uint_as_float(hp.x << 16);
    float f1 = __uint_as_float(hp.x & 0xFFFF0000u);
    float f2 = __uint_as_float(hp.y << 16);
    float f3 = __uint_as_float(hp.y & 0xFFFF0000u);
    float a0 = 0.f, a1 = 0.f, a2 = 0.f, a3 = 0.f;
    for (int base = s0; base < s1; base += 64) {
        int m = s1 - base;
        if (m > 64) m = 64;
        int idx = (lane < m) ? by_row[base + lane] : u;   // self -> d = 0
        for (int j = 0; j < m; j += 16) {
            #pragma unroll
            for (int p = 0; p < 4; ++p) {
                int jj = j + 4 * p + q;                   // <= 63 always
                int e = __shfl(idx, jj);
                uint2 v = ((const uint2*)hb)[((size_t)e << 4) + fl];
                float d0 = f0 - __uint_as_float(v.x << 16);
                float d1 = f1 - __uint_as_float(v.x & 0xFFFF0000u);
                float d2 = f2 - __uint_as_float(v.y << 16);
                float d3 = f3 - __uint_as_float(v.y & 0xFFFF0000u);
                a0 += d0 * d0; a1 += d1 * d1;
                a2 += d2 * d2; a3 += d3 * d3;
            }
        }
    }
    a0 += __shfl_xor(a0, 16); a0 += __shfl_xor(a0, 32);
    a1 += __shfl_xor(a1, 16); a1 += __shfl_xor(a1, 32);
    a2 += __shfl_xor(a2, 16); a2 += __shfl_xor(a2, 32);
    a3 += __shfl_xor(a3, 16); a3 += __shfl_xor(a3, 32);
    if (lane < 16) {
        float inv = 1.f / fmaxf((float)(s1 - s0), 1.f);
        float4 o;
        o.x = tanhf(a0 * inv);
        o.y = tanhf(a1 * inv);
        o.z = tanhf(a2 * inv);
        o.w = tanhf(a3 * inv);
        ((float4*)out)[((size_t)u << 4) + fl] = o;
    }
}

extern "C" void kernel_launch(void* const* d_in, const int* in_sizes, int n_in,
                              void* d_out, int out_size, void* d_ws, size_t ws_size,
                              hipStream_t stream) {
    const float* X  = (const float*)d_in[0];
    const int*   ei = (const int*)d_in[1];
    const float* Wl = (const float*)d_in[2];
    const float* Wr = (const float*)d_in[3];
    const float* b  = (const float*)d_in[4];
    float* out = (float*)d_out;

    int n = in_sizes[0] / D;
    int n_edges = in_sizes[1] / 2;
    int nbk = (n + 127) >> 7;
    int nchunks = (n_edges + CHUNK - 1) / CHUNK;

    // ws layout (~72 MB); xb has n+1 rows (row n = zeros)
    float* agg = (float*)d_ws;                                       // n*64 f32
    unsigned* xb = (unsigned*)(agg + (size_t)n * D);                 // (n+1)*32
    unsigned* hbuf = xb + (size_t)(n + 1) * 32;                      // n*32 u32
    unsigned short* wpack = (unsigned short*)(hbuf + (size_t)n * 32);// 16384
    int* w = (int*)(wpack + 16384);
    int* bc_col    = w;                    // nbk
    int* bc_row    = bc_col + nbk;         // nbk
    int* bbase_col = bc_row + nbk;         // nbk
    int* bbase_row = bbase_col + nbk;      // nbk
    int* gcur_col  = bbase_row + nbk;      // nbk
    int* gcur_row  = gcur_col + nbk;       // nbk
    int* off_col   = gcur_row + nbk;       // n+1
    int* off_row   = off_col + (n + 1);    // n+1
    unsigned* ecol = (unsigned*)(off_row + (n + 1));   // n_edges
    unsigned* erow = ecol + n_edges;                   // n_edges
    int* by_col = (int*)(erow + n_edges);              // n_edges
    int* by_row = by_col + n_edges;                    // n_edges

    hipMemsetAsync(bc_col, 0, (size_t)2 * nbk * sizeof(int), stream);

    int total = n * 32, total2 = (n + 1) * 32;
    convert_x<<<(total2 + 255) / 256, 256, 0, stream>>>(X, xb, total, total2);
    bucket_hist<<<nchunks, MS_T, 0, stream>>>(ei, n_edges, nbk, bc_col, bc_row);
    bucket_scan<<<1, 64, 0, stream>>>(bc_col, bc_row, bbase_col, bbase_row,
                                      gcur_col, gcur_row, nbk);
    multisplit<<<nchunks, MS_T, 0, stream>>>(ei, n_edges, nbk,
                                             gcur_col, gcur_row, ecol, erow);
    csr_build<<<2 * nbk, 256, 0, stream>>>(ecol, erow, bbase_col, bbase_row,
                                           bc_col, bc_row, off_col, off_row,
                                           by_col, by_row, n, nbk);

    pack_w<<<1, 256, 0, stream>>>(Wl, Wr, wpack);

    agg_gather<<<(n + 3) / 4, 256, 0, stream>>>(xb, off_col, by_col, agg, n);

    int ngroups = (n + 15) / 16;
    linear_mfma<<<(ngroups + 3) / 4, 256, 0, stream>>>(X, agg, wpack, b, hbuf,
                                                       n, ngroups);

    gate_kernel<<<(n + 3) / 4, 256, 0, stream>>>(hbuf, off_row, by_row, out, n);
}

// Round 11
// 245.974 us; speedup vs baseline: 7.6587x; 1.0456x over previous
//
#include <hip/hip_runtime.h>
#include <math.h>

#define D 64
#define CHUNK 8192
#define MS_T 1024
#define EPT 8           // CHUNK / MS_T
#define MAXNB 800       // >= nbk = ceil(n/128); n=100000 -> 782

typedef __attribute__((ext_vector_type(8))) short frag_ab;
typedef __attribute__((ext_vector_type(4))) float frag_cd;
typedef __attribute__((ext_vector_type(2))) float v2f;

__device__ __forceinline__ unsigned short f2bf(float f) {
    unsigned u = __float_as_uint(f);
    u += 0x7FFFu + ((u >> 16) & 1u);
    return (unsigned short)(u >> 16);
}
__device__ __forceinline__ float bf2f(unsigned short s) {
    return __uint_as_float(((unsigned)s) << 16);
}
// tanh for x >= 0, branch-free, ~5 VALU (vs ~20+ for library tanhf).
// |err| ~ 1e-6 vs absmax budget 2e-2.
__device__ __forceinline__ float fast_tanh_pos(float x) {
    float t = __expf(-2.0f * x);
    return (1.0f - t) * __builtin_amdgcn_rcpf(1.0f + t);
}

// ---------------------------------------------------------------------------
// convert_x (+ pack_w folded into the last block).
// X (fp32) -> packed bf16 pairs; row n = zeros (branch-free masked target).
// ---------------------------------------------------------------------------
__global__ __launch_bounds__(256) void convert_x(
    const float* __restrict__ X, unsigned* __restrict__ xb, int total,
    int total2, const float* __restrict__ Wl, const float* __restrict__ Wr,
    unsigned short* __restrict__ wpack)
{
    if (blockIdx.x == gridDim.x - 1) {          // pack_w (R4-verified layout)
        for (int c = threadIdx.x; c < 8192; c += 256) {
            int j = c & 7;
            int lane = (c >> 3) & 63;
            int tile = (c >> 9) & 7;
            int mat = c >> 12;
            int kc = tile >> 2;
            int nt = tile & 3;
            int krow = (lane >> 4) * 8 + j + kc * 32;
            int col = (lane & 15) + nt * 16;
            const float* W = mat ? Wr : Wl;
            float v = W[krow * 64 + col];
            unsigned short hi = f2bf(v);
            unsigned short lo = f2bf(v - bf2f(hi));
            int base = mat * 8192 + tile * 512 + lane * 8 + j;
            wpack[base] = hi;
            wpack[base + 4096] = lo;
        }
        return;
    }
    int i = blockIdx.x * blockDim.x + threadIdx.x;
    if (i >= total2) return;
    if (i < total) {
        float2 v = ((const float2*)X)[i];
        xb[i] = (unsigned)f2bf(v.x) | ((unsigned)f2bf(v.y) << 16);
    } else {
        xb[i] = 0u;
    }
}

// ---------------------------------------------------------------------------
// Per-chunk LDS histogram over 128-node buckets (verified)
// ---------------------------------------------------------------------------
__global__ __launch_bounds__(MS_T) void bucket_hist(
    const int* __restrict__ ei, int n_edges, int nbk,
    int* __restrict__ bc_col, int* __restrict__ bc_row)
{
    __shared__ int scol[MAXNB];
    __shared__ int srow[MAXNB];
    for (int t = threadIdx.x; t < nbk; t += MS_T) {
        scol[t] = 0;
        srow[t] = 0;
    }
    __syncthreads();

    int base = blockIdx.x * CHUNK;
    int cc = n_edges - base;
    if (cc > CHUNK) cc = CHUNK;
    #pragma unroll
    for (int k = 0; k < EPT; ++k) {
        int i = threadIdx.x + k * MS_T;
        if (i < cc) {
            int r = ei[base + i];
            int c = ei[n_edges + base + i];
            atomicAdd(&srow[r >> 7], 1);
            atomicAdd(&scol[c >> 7], 1);
        }
    }
    __syncthreads();
    for (int t = threadIdx.x; t < nbk; t += MS_T) {
        if (scol[t]) atomicAdd(&bc_col[t], scol[t]);
        if (srow[t]) atomicAdd(&bc_row[t], srow[t]);
    }
}

// ---------------------------------------------------------------------------
// scan 782 bucket counts -> bases; init cursors (verified)
// ---------------------------------------------------------------------------
__global__ __launch_bounds__(64) void bucket_scan(
    const int* __restrict__ bc_col, const int* __restrict__ bc_row,
    int* __restrict__ bbase_col, int* __restrict__ bbase_row,
    int* __restrict__ gcur_col, int* __restrict__ gcur_row, int nbk)
{
    int lane = threadIdx.x;
    for (int w = 0; w < 2; ++w) {
        const int* bc = w ? bc_row : bc_col;
        int* bb = w ? bbase_row : bbase_col;
        int* gc = w ? gcur_row : gcur_col;
        int carry = 0;
        for (int b0 = 0; b0 < nbk; b0 += 64) {
            int v = (b0 + lane < nbk) ? bc[b0 + lane] : 0;
            int x = v;
            #pragma unroll
            for (int o = 1; o < 64; o <<= 1) {
                int u = __shfl_up(x, o);
                if (lane >= o) x += u;
            }
            if (b0 + lane < nbk) {
                int e = carry + x - v;
                bb[b0 + lane] = e;
                gc[b0 + lane] = e;
            }
            carry += __shfl(x, 63);
        }
    }
}

// ---------------------------------------------------------------------------
// Multisplit (verified): group edges into 128-node buckets, both orders.
// ---------------------------------------------------------------------------
__global__ __launch_bounds__(MS_T) void multisplit(
    const int* __restrict__ ei, int n_edges, int nbk,
    int* __restrict__ gcur_col, int* __restrict__ gcur_row,
    unsigned* __restrict__ ecol, unsigned* __restrict__ erow)
{
    __shared__ unsigned stage[CHUNK];
    __shared__ unsigned short sbk[CHUNK];
    __shared__ int cnt[MAXNB];
    __shared__ int off[MAXNB + 1];
    __shared__ int gb[MAXNB];

    int base = blockIdx.x * CHUNK;
    int cc = n_edges - base;
    if (cc > CHUNK) cc = CHUNK;

    int r[EPT], c[EPT];
    #pragma unroll
    for (int k = 0; k < EPT; ++k) {
        int i = threadIdx.x + k * MS_T;
        if (i < cc) {
            r[k] = ei[base + i];
            c[k] = ei[n_edges + base + i];
        }
    }

    for (int ord = 0; ord < 2; ++ord) {
        int* gcur = ord ? gcur_row : gcur_col;
        unsigned* eout = ord ? erow : ecol;

        for (int t = threadIdx.x; t < nbk; t += MS_T) cnt[t] = 0;
        __syncthreads();

        int rk[EPT], bk[EPT];
        #pragma unroll
        for (int k = 0; k < EPT; ++k) {
            int i = threadIdx.x + k * MS_T;
            if (i < cc) {
                int key = ord ? r[k] : c[k];
                bk[k] = key >> 7;
                rk[k] = atomicAdd(&cnt[bk[k]], 1);
            }
        }
        __syncthreads();

        if (threadIdx.x < 64) {           // wave 0: scan + global reservation
            int lane = threadIdx.x;
            int carry = 0;
            for (int b0 = 0; b0 < nbk; b0 += 64) {
                int v = (b0 + lane < nbk) ? cnt[b0 + lane] : 0;
                int x = v;
                #pragma unroll
                for (int o = 1; o < 64; o <<= 1) {
                    int u = __shfl_up(x, o);
                    if (lane >= o) x += u;
                }
                if (b0 + lane < nbk) {
                    off[b0 + lane] = carry + x - v;
                    gb[b0 + lane] = v ? atomicAdd(&gcur[b0 + lane], v) : 0;
                }
                carry += __shfl(x, 63);
            }
        }
        __syncthreads();

        #pragma unroll
        for (int k = 0; k < EPT; ++k) {
            int i = threadIdx.x + k * MS_T;
            if (i < cc) {
                int key = ord ? r[k] : c[k];
                int oth = ord ? c[k] : r[k];
                int p = off[bk[k]] + rk[k];
                stage[p] = ((unsigned)(key & 127) << 17) | (unsigned)oth;
                sbk[p] = (unsigned short)bk[k];
            }
        }
        __syncthreads();

        for (int t = threadIdx.x; t < cc; t += MS_T) {
            int bb = sbk[t];
            eout[gb[bb] + (t - off[bb])] = stage[t];
        }
        __syncthreads();
    }
}

// ---------------------------------------------------------------------------
// csr_build (verified): bucket entries -> exact per-node CSR.
// ---------------------------------------------------------------------------
__global__ __launch_bounds__(256) void csr_build(
    const unsigned* __restrict__ ecol, const unsigned* __restrict__ erow,
    const int* __restrict__ bbase_col, const int* __restrict__ bbase_row,
    const int* __restrict__ bc_col, const int* __restrict__ bc_row,
    int* __restrict__ off_col, int* __restrict__ off_row,
    int* __restrict__ by_col, int* __restrict__ by_row, int n, int nbk)
{
    __shared__ int scnt[128];
    __shared__ int soff[129];
    bool isRow = blockIdx.x >= (unsigned)nbk;
    int b = isRow ? (blockIdx.x - nbk) : blockIdx.x;
    const unsigned* e = isRow ? erow : ecol;
    int base = (isRow ? bbase_row : bbase_col)[b];
    int ec = (isRow ? bc_row : bc_col)[b];
    int* off_g = isRow ? off_row : off_col;
    int* by = isRow ? by_row : by_col;

    int node0 = b << 7;
    int nn = n - node0;
    if (nn > 128) nn = 128;

    if (threadIdx.x < 128) scnt[threadIdx.x] = 0;
    __syncthreads();

    for (int t = threadIdx.x; t < ec; t += 256)
        atomicAdd(&scnt[e[base + t] >> 17], 1);
    __syncthreads();

    if (threadIdx.x < 64) {
        int lane = threadIdx.x;
        int carry = 0;
        #pragma unroll
        for (int b0 = 0; b0 < 128; b0 += 64) {
            int v = scnt[b0 + lane];
            int x = v;
            #pragma unroll
            for (int o = 1; o < 64; o <<= 1) {
                int u = __shfl_up(x, o);
                if (lane >= o) x += u;
            }
            soff[b0 + lane] = carry + x - v;
            carry += __shfl(x, 63);
        }
        if (lane == 63) soff[128] = carry;
    }
    __syncthreads();

    if (threadIdx.x < 128) {
        if (threadIdx.x < nn) off_g[node0 + threadIdx.x] = base + soff[threadIdx.x];
        scnt[threadIdx.x] = 0;
    }
    if (threadIdx.x == 0 && node0 + nn == n) off_g[n] = base + soff[nn];
    __syncthreads();

    for (int t = threadIdx.x; t < ec; t += 256) {
        unsigned ent = e[base + t];
        int slot = ent >> 17;
        int r = atomicAdd(&scnt[slot], 1);
        by[base + soff[slot] + r] = (int)(ent & 0x1FFFF);
    }
}

// ---------------------------------------------------------------------------
// CSR mean-aggregate: 16 lanes/edge, uint2 loads, p-unroll 4, branch-free,
// packed-fp32 accumulate (v_pk_add_f32).
// ---------------------------------------------------------------------------
__global__ __launch_bounds__(256) void agg_gather(
    const unsigned* __restrict__ xb, const int* __restrict__ off_col,
    const int* __restrict__ by_col, float* __restrict__ agg, int n)
{
    int lane = threadIdx.x & 63;
    int node = (blockIdx.x * blockDim.x + threadIdx.x) >> 6;
    if (node >= n) return;
    int fl = lane & 15, q = lane >> 4;
    int s0 = off_col[node], s1 = off_col[node + 1];
    v2f a01 = {0.f, 0.f}, a23 = {0.f, 0.f};
    for (int base = s0; base < s1; base += 64) {
        int m = s1 - base;
        if (m > 64) m = 64;
        int idx = (lane < m) ? by_col[base + lane] : n;   // row n = zeros
        for (int j = 0; j < m; j += 16) {
            #pragma unroll
            for (int p = 0; p < 4; ++p) {
                int jj = j + 4 * p + q;                   // <= 63 always
                int e = __shfl(idx, jj);
                uint2 v = ((const uint2*)xb)[((size_t)e << 4) + fl];
                v2f h01, h23;
                h01.x = __uint_as_float(v.x << 16);
                h01.y = __uint_as_float(v.x & 0xFFFF0000u);
                h23.x = __uint_as_float(v.y << 16);
                h23.y = __uint_as_float(v.y & 0xFFFF0000u);
                a01 += h01;                               // v_pk_add_f32
                a23 += h23;
            }
        }
    }
    a01.x += __shfl_xor(a01.x, 16); a01.x += __shfl_xor(a01.x, 32);
    a01.y += __shfl_xor(a01.y, 16); a01.y += __shfl_xor(a01.y, 32);
    a23.x += __shfl_xor(a23.x, 16); a23.x += __shfl_xor(a23.x, 32);
    a23.y += __shfl_xor(a23.y, 16); a23.y += __shfl_xor(a23.y, 32);
    if (lane < 16) {
        float inv = 1.f / fmaxf((float)(s1 - s0), 1.f);
        float4 o;
        o.x = a01.x * inv; o.y = a01.y * inv;
        o.z = a23.x * inv; o.w = a23.y * inv;
        ((float4*)agg)[((size_t)node << 4) + fl] = o;
    }
}

// ---------------------------------------------------------------------------
// linear_mfma (verified math); epilogue writes packed-bf16 hb only.
// ---------------------------------------------------------------------------
__global__ __launch_bounds__(256) void linear_mfma(
    const float* __restrict__ X, const float* __restrict__ agg,
    const unsigned short* __restrict__ wpack, const float* __restrict__ b,
    unsigned* __restrict__ hb, int n, int ngroups)
{
    int lane = threadIdx.x & 63;
    int g = (blockIdx.x * blockDim.x + threadIdx.x) >> 6;
    if (g >= ngroups) return;
    int quad = lane >> 4;
    int l15 = lane & 15;

    frag_ab wf[2][2][2][4];
    #pragma unroll
    for (int mat = 0; mat < 2; ++mat)
        #pragma unroll
        for (int hf = 0; hf < 2; ++hf)
            #pragma unroll
            for (int kc = 0; kc < 2; ++kc)
                #pragma unroll
                for (int nt = 0; nt < 4; ++nt) {
                    const unsigned short* p =
                        wpack + mat * 8192 + hf * 4096 + (kc * 4 + nt) * 512 + lane * 8;
                    wf[mat][hf][kc][nt] = *(const frag_ab*)p;
                }

    frag_cd acc[4];
    #pragma unroll
    for (int nt = 0; nt < 4; ++nt) acc[nt] = (frag_cd){0.f, 0.f, 0.f, 0.f};

    int mrow = g * 16 + l15;
    if (mrow >= n) mrow = n - 1;
    const float* arow = agg + ((size_t)mrow << 6) + quad * 8;
    const float* xrow = X + ((size_t)mrow << 6) + quad * 8;

    #pragma unroll
    for (int kc = 0; kc < 2; ++kc) {
        float av[8], xv[8];
        #pragma unroll
        for (int t = 0; t < 2; ++t) {
            float4 a4 = *(const float4*)(arow + kc * 32 + t * 4);
            float4 x4 = *(const float4*)(xrow + kc * 32 + t * 4);
            av[t * 4 + 0] = a4.x; av[t * 4 + 1] = a4.y;
            av[t * 4 + 2] = a4.z; av[t * 4 + 3] = a4.w;
            xv[t * 4 + 0] = x4.x; xv[t * 4 + 1] = x4.y;
            xv[t * 4 + 2] = x4.z; xv[t * 4 + 3] = x4.w;
        }
        frag_ab ah, al, xh, xl;
        #pragma unroll
        for (int j = 0; j < 8; ++j) {
            unsigned short hbv = f2bf(av[j]);
            ah[j] = (short)hbv;
            al[j] = (short)f2bf(av[j] - bf2f(hbv));
            unsigned short xbv = f2bf(xv[j]);
            xh[j] = (short)xbv;
            xl[j] = (short)f2bf(xv[j] - bf2f(xbv));
        }
        #pragma unroll
        for (int nt = 0; nt < 4; ++nt) {
            acc[nt] = __builtin_amdgcn_mfma_f32_16x16x32_bf16(ah, wf[0][0][kc][nt], acc[nt], 0, 0, 0);
            acc[nt] = __builtin_amdgcn_mfma_f32_16x16x32_bf16(ah, wf[0][1][kc][nt], acc[nt], 0, 0, 0);
            acc[nt] = __builtin_amdgcn_mfma_f32_16x16x32_bf16(al, wf[0][0][kc][nt], acc[nt], 0, 0, 0);
            acc[nt] = __builtin_amdgcn_mfma_f32_16x16x32_bf16(xh, wf[1][0][kc][nt], acc[nt], 0, 0, 0);
            acc[nt] = __builtin_amdgcn_mfma_f32_16x16x32_bf16(xh, wf[1][1][kc][nt], acc[nt], 0, 0, 0);
            acc[nt] = __builtin_amdgcn_mfma_f32_16x16x32_bf16(xl, wf[1][0][kc][nt], acc[nt], 0, 0, 0);
        }
    }

    #pragma unroll
    for (int nt = 0; nt < 4; ++nt) {
        float bj = b[l15 + nt * 16];
        #pragma unroll
        for (int r = 0; r < 4; ++r) {
            int row = quad * 4 + r;
            int node = g * 16 + row;
            float v = fmaxf(acc[nt][r] + bj, 0.f);
            float vn = __shfl_xor(v, 1);          // neighbor feature (l15^1)
            if (((l15 & 1) == 0) && node < n) {
                unsigned pk = (unsigned)f2bf(v) | ((unsigned)f2bf(vn) << 16);
                hb[((size_t)node << 5) + ((nt * 16 + l15) >> 1)] = pk;
            }
        }
    }
}

// ---------------------------------------------------------------------------
// Gate: 16 lanes/edge, uint2 loads, p-unroll 4, branch-free (masked -> self,
// d = 0 exactly), packed-fp32 math (v_pk_add/v_pk_fma), fast tanh.
// ---------------------------------------------------------------------------
__global__ __launch_bounds__(256) void gate_kernel(
    const unsigned* __restrict__ hb, const int* __restrict__ off_row,
    const int* __restrict__ by_row, float* __restrict__ out, int n)
{
    int lane = threadIdx.x & 63;
    int u = (blockIdx.x * blockDim.x + threadIdx.x) >> 6;
    if (u >= n) return;
    int fl = lane & 15, q = lane >> 4;
    int s0 = off_row[u], s1 = off_row[u + 1];
    uint2 hp = ((const uint2*)hb)[((size_t)u << 4) + fl];
    v2f f01, f23;
    f01.x = __uint_as_float(hp.x << 16);
    f01.y = __uint_as_float(hp.x & 0xFFFF0000u);
    f23.x = __uint_as_float(hp.y << 16);
    f23.y = __uint_as_float(hp.y & 0xFFFF0000u);
    v2f a01 = {0.f, 0.f}, a23 = {0.f, 0.f};
    for (int base = s0; base < s1; base += 64) {
        int m = s1 - base;
        if (m > 64) m = 64;
        int idx = (lane < m) ? by_row[base + lane] : u;   // self -> d = 0
        for (int j = 0; j < m; j += 16) {
            #pragma unroll
            for (int p = 0; p < 4; ++p) {
                int jj = j + 4 * p + q;                   // <= 63 always
                int e = __shfl(idx, jj);
                uint2 v = ((const uint2*)hb)[((size_t)e << 4) + fl];
                v2f h01, h23;
                h01.x = __uint_as_float(v.x << 16);
                h01.y = __uint_as_float(v.x & 0xFFFF0000u);
                h23.x = __uint_as_float(v.y << 16);
                h23.y = __uint_as_float(v.y & 0xFFFF0000u);
                v2f d01 = f01 - h01;                      // v_pk_add (neg)
                v2f d23 = f23 - h23;
                a01 += d01 * d01;                         // v_pk_fma
                a23 += d23 * d23;
            }
        }
    }
    a01.x += __shfl_xor(a01.x, 16); a01.x += __shfl_xor(a01.x, 32);
    a01.y += __shfl_xor(a01.y, 16); a01.y += __shfl_xor(a01.y, 32);
    a23.x += __shfl_xor(a23.x, 16); a23.x += __shfl_xor(a23.x, 32);
    a23.y += __shfl_xor(a23.y, 16); a23.y += __shfl_xor(a23.y, 32);
    if (lane < 16) {
        float inv = 1.f / fmaxf((float)(s1 - s0), 1.f);
        float4 o;
        o.x = fast_tanh_pos(a01.x * inv);
        o.y = fast_tanh_pos(a01.y * inv);
        o.z = fast_tanh_pos(a23.x * inv);
        o.w = fast_tanh_pos(a23.y * inv);
        ((float4*)out)[((size_t)u << 4) + fl] = o;
    }
}

extern "C" void kernel_launch(void* const* d_in, const int* in_sizes, int n_in,
                              void* d_out, int out_size, void* d_ws, size_t ws_size,
                              hipStream_t stream) {
    const float* X  = (const float*)d_in[0];
    const int*   ei = (const int*)d_in[1];
    const float* Wl = (const float*)d_in[2];
    const float* Wr = (const float*)d_in[3];
    const float* b  = (const float*)d_in[4];
    float* out = (float*)d_out;

    int n = in_sizes[0] / D;
    int n_edges = in_sizes[1] / 2;
    int nbk = (n + 127) >> 7;
    int nchunks = (n_edges + CHUNK - 1) / CHUNK;

    // ws layout (~72 MB); xb has n+1 rows (row n = zeros)
    float* agg = (float*)d_ws;                                       // n*64 f32
    unsigned* xb = (unsigned*)(agg + (size_t)n * D);                 // (n+1)*32
    unsigned* hbuf = xb + (size_t)(n + 1) * 32;                      // n*32 u32
    unsigned short* wpack = (unsigned short*)(hbuf + (size_t)n * 32);// 16384
    int* w = (int*)(wpack + 16384);
    int* bc_col    = w;                    // nbk
    int* bc_row    = bc_col + nbk;         // nbk
    int* bbase_col = bc_row + nbk;         // nbk
    int* bbase_row = bbase_col + nbk;      // nbk
    int* gcur_col  = bbase_row + nbk;      // nbk
    int* gcur_row  = gcur_col + nbk;       // nbk
    int* off_col   = gcur_row + nbk;       // n+1
    int* off_row   = off_col + (n + 1);    // n+1
    unsigned* ecol = (unsigned*)(off_row + (n + 1));   // n_edges
    unsigned* erow = ecol + n_edges;                   // n_edges
    int* by_col = (int*)(erow + n_edges);              // n_edges
    int* by_row = by_col + n_edges;                    // n_edges

    hipMemsetAsync(bc_col, 0, (size_t)2 * nbk * sizeof(int), stream);

    int total = n * 32, total2 = (n + 1) * 32;
    convert_x<<<(total2 + 255) / 256 + 1, 256, 0, stream>>>(
        X, xb, total, total2, Wl, Wr, wpack);
    bucket_hist<<<nchunks, MS_T, 0, stream>>>(ei, n_edges, nbk, bc_col, bc_row);
    bucket_scan<<<1, 64, 0, stream>>>(bc_col, bc_row, bbase_col, bbase_row,
                                      gcur_col, gcur_row, nbk);
    multisplit<<<nchunks, MS_T, 0, stream>>>(ei, n_edges, nbk,
                                             gcur_col, gcur_row, ecol, erow);
    csr_build<<<2 * nbk, 256, 0, stream>>>(ecol, erow, bbase_col, bbase_row,
                                           bc_col, bc_row, off_col, off_row,
                                           by_col, by_row, n, nbk);

    agg_gather<<<(n + 3) / 4, 256, 0, stream>>>(xb, off_col, by_col, agg, n);

    int ngroups = (n + 15) / 16;
    linear_mfma<<<(ngroups + 3) / 4, 256, 0, stream>>>(X, agg, wpack, b, hbuf,
                                                       n, ngroups);

    gate_kernel<<<(n + 3) / 4, 256, 0, stream>>>(hbuf, off_row, by_row, out, n);
}